// Round 1
// baseline (113032.825 us; speedup 1.0000x reference)
//
#include <hip/hip_runtime.h>
#include <math.h>

// ---------------------------------------------------------------------------
// helpers
// ---------------------------------------------------------------------------
__device__ __forceinline__ float sigm(float x) { return 1.0f / (1.0f + __expf(-x)); }

__device__ __forceinline__ float waveSum(float v) {
#pragma unroll
  for (int off = 32; off > 0; off >>= 1) v += __shfl_xor(v, off);
  return v;
}

// ---------------------------------------------------------------------------
// char CNN + elmo concat  -> x_all (4224 x 356)
// ---------------------------------------------------------------------------
__global__ __launch_bounds__(128) void cnn_embed_kernel(
    const int* __restrict__ chars_ctx, const int* __restrict__ chars_qry,
    const float* __restrict__ elmo_ctx, const float* __restrict__ elmo_qry,
    const float* __restrict__ char_emb, const float* __restrict__ conv_w,
    const float* __restrict__ conv_b, float* __restrict__ x_all)
{
  int n = blockIdx.x;
  const int*   chars = (n < 4096) ? (chars_ctx + n * 16) : (chars_qry + (n - 4096) * 16);
  const float* elmo  = (n < 4096) ? (elmo_ctx + (size_t)n * 256)
                                  : (elmo_qry + (size_t)(n - 4096) * 256);
  __shared__ float xl[1600];   // [emb_dim=100][pos=16]
  __shared__ int   cidx[16];
  int tid = threadIdx.x;
  if (tid < 16) cidx[tid] = chars[tid];
  __syncthreads();
  for (int e = tid; e < 1600; e += 128) {
    int i = e >> 4, p = e & 15;
    xl[e] = char_emb[cidx[p] * 100 + i];
  }
  __syncthreads();
  if (tid < 100) {
    int o = tid;
    float acc[16];
#pragma unroll
    for (int p = 0; p < 16; ++p) acc[p] = 0.f;
    const float* wo = conv_w + o * 500;
    for (int i = 0; i < 100; ++i) {
      const float* xi = xl + i * 16;
#pragma unroll
      for (int k = 0; k < 5; ++k) {
        float w = wo[i * 5 + k];
#pragma unroll
        for (int p = 0; p < 16; ++p) {
          int src = p + k - 2;
          if (src >= 0 && src < 16) acc[p] += w * xi[src];
        }
      }
    }
    float m = acc[0];
#pragma unroll
    for (int p = 1; p < 16; ++p) m = fmaxf(m, acc[p]);
    x_all[(size_t)n * 356 + o] = m + conv_b[o];
  }
  for (int j = tid; j < 256; j += 128)
    x_all[(size_t)n * 356 + 100 + j] = elmo[j];
}

// ---------------------------------------------------------------------------
// generic fp32 GEMM:  C[M,N] = A[M,K] @ B[N,K]^T + bias[N]
// ---------------------------------------------------------------------------
#define BMT 64
#define BNT 64
#define BKT 16

__global__ __launch_bounds__(256) void gemm_abt(
    const float* __restrict__ A, const float* __restrict__ B,
    const float* __restrict__ bias, float* __restrict__ C,
    int M, int N, int K)
{
  __shared__ float As[BKT][BMT + 4];
  __shared__ float Bs[BKT][BNT + 4];
  int tid = threadIdx.x;
  int bm = blockIdx.y * BMT, bn = blockIdx.x * BNT;
  int tm = (tid >> 4) << 2;
  int tn = (tid & 15) << 2;
  float acc[4][4];
#pragma unroll
  for (int i = 0; i < 4; ++i)
#pragma unroll
    for (int j = 0; j < 4; ++j) acc[i][j] = 0.f;

  for (int k0 = 0; k0 < K; k0 += BKT) {
    for (int e = tid; e < BMT * BKT; e += 256) {
      int m = e >> 4, kk = e & 15;
      int gm = bm + m, gk = k0 + kk;
      As[kk][m] = (gm < M && gk < K) ? A[(size_t)gm * K + gk] : 0.f;
    }
    for (int e = tid; e < BNT * BKT; e += 256) {
      int nn = e >> 4, kk = e & 15;
      int gn = bn + nn, gk = k0 + kk;
      Bs[kk][nn] = (gn < N && gk < K) ? B[(size_t)gn * K + gk] : 0.f;
    }
    __syncthreads();
#pragma unroll
    for (int kk = 0; kk < BKT; ++kk) {
      float a[4], b[4];
#pragma unroll
      for (int i = 0; i < 4; ++i) a[i] = As[kk][tm + i];
#pragma unroll
      for (int j = 0; j < 4; ++j) b[j] = Bs[kk][tn + j];
#pragma unroll
      for (int i = 0; i < 4; ++i)
#pragma unroll
        for (int j = 0; j < 4; ++j) acc[i][j] += a[i] * b[j];
    }
    __syncthreads();
  }
#pragma unroll
  for (int i = 0; i < 4; ++i) {
    int gm = bm + tm + i;
    if (gm >= M) continue;
#pragma unroll
    for (int j = 0; j < 4; ++j) {
      int gn = bn + tn + j;
      if (gn < N) {
        float v = acc[i][j];
        if (bias) v += bias[gn];
        C[(size_t)gm * N + gn] = v;
      }
    }
  }
}

// ---------------------------------------------------------------------------
// highway combine
// ---------------------------------------------------------------------------
__global__ void highway_combine(float* __restrict__ x, const float* __restrict__ g,
                                const float* __restrict__ p, int total)
{
  int i = blockIdx.x * blockDim.x + threadIdx.x;
  if (i < total) {
    float gg = sigm(g[i]);
    float pp = fmaxf(p[i], 0.f);
    x[i] = gg * pp + (1.f - gg) * x[i];
  }
}

// ---------------------------------------------------------------------------
// persistent BiLSTM scan kernel, v3: fully wave-autonomous step loop.
//
// Unit-major ownership: wave wv of WG wg owns NU=3 hidden units
// j = wg*SLICE + wv*NU + u. All 4 gate rows of a unit live IN the same wave
// (12 Whh rows x 6 lane-chunks in VGPRs), so after an interleaved 12-row
// butterfly waveSum, lane u computes c/h and publishes the packed
// {epoch|h} u64 immediately — no __syncthreads anywhere in the step loop.
// Each lane then polls its 6 exchange words (k = lane + 64*ii) straight
// into registers (coalesced 512B/wave atomic loads) for the next step's
// dots — no LDS at all. Waves that own zero valid units exit before the
// loop so the epoch-parity progression invariant (a publisher cannot lap
// any reader) still holds. Numerics are bit-identical to v2.
//
// A second, independent scan problem (the 128-step query scan) can ride
// along in blocks [2*NWG, 4*NWG) of the same dispatch.
// ---------------------------------------------------------------------------
#define NWG 16
#define SLICE 23   // 16*23 = 368 >= 356
#define NU 3       // units per wave (8 waves * 3 = 24 >= 23)

__global__ __launch_bounds__(512, 1) void lstm_scan_kernel(
    const float* __restrict__ xw, const float* __restrict__ whh,
    const float* __restrict__ h0, float* __restrict__ out,
    int row0, int N, unsigned long long* exbuf,
    const float* __restrict__ h0b, int row0b, int Nb,
    unsigned long long* exbufb)
{
  int bid = blockIdx.x;
  if (bid >= 2 * NWG) {          // optional second problem
    bid -= 2 * NWG;
    h0 = h0b; row0 = row0b; N = Nb; exbuf = exbufb;
    if (N <= 0) return;
  }
  const int tid  = threadIdx.x;
  const int dir  = bid & 1;
  const int wg   = bid >> 1;
  const int lane = tid & 63;
  const int wv   = tid >> 6;          // 0..7
  const int j0   = wg * SLICE;
  const int base_u = wv * NU;
  const float* whh_d = whh + (size_t)dir * 1424 * 356;
  const float* h0_d  = h0 + dir * 356;
  const int xcol0 = dir * 1424;
  const int ocol0 = dir * 356;
  unsigned long long* exd = exbuf + (size_t)dir * 712;   // [parity][356]

  // number of valid units owned by this wave (prefix-valid)
  int nu = 0;
#pragma unroll
  for (int u = 0; u < NU; ++u) {
    int uu = base_u + u;
    if (uu < SLICE && (j0 + uu) < 356) nu = u + 1;
  }
  if (nu == 0) return;   // owns nothing, publishes nothing -> must not poll

  // Whh rows -> registers. Row q = u*4 + g covers gate g of unit j0+base_u+u.
  float wreg[12][6];
#pragma unroll
  for (int q = 0; q < 12; ++q) {
    int u = q >> 2, g = q & 3;
    bool v = (u < nu);
    int j = j0 + base_u + (v ? u : 0);
    const float* wrow = whh_d + (size_t)(g * 356 + j) * 356;
#pragma unroll
    for (int ii = 0; ii < 6; ++ii) {
      int k = lane + ii * 64;
      wreg[q][ii] = (v && k < 356) ? wrow[k] : 0.f;
    }
  }

  // h state in registers: hreg[ii] = h[lane + 64*ii]
  float hreg[6];
#pragma unroll
  for (int ii = 0; ii < 6; ++ii) {
    int k = lane + ii * 64;
    hreg[ii] = (k < 356) ? h0_d[k] : 0.f;
  }

  // cell state: lane u holds c for its unit
  float c_reg = 0.f;
  if (lane < nu) c_reg = h0_d[j0 + base_u + lane];

  // xw duty: lane q (q<12, u=q>>2 valid) holds xw for row (gate q&3, unit u)
  const bool xvalid = (lane < 12) && ((lane >> 2) < nu);
  size_t xcol = 0;
  if (xvalid) xcol = (size_t)(xcol0 + (lane & 3) * 356 + (j0 + base_u + (lane >> 2)));

  float xw_cur = 0.f;
  {
    int row = dir ? (N - 1) : 0;
    if (xvalid) xw_cur = xw[(size_t)(row0 + row) * 2848 + xcol];
  }

  for (int t = 0; t < N; ++t) {
    int row = dir ? (N - 1 - t) : t;
    size_t grow = (size_t)(row0 + row);

    // issue next-step xw prefetch first (covered by this step's compute+poll)
    float xw_nx = 0.f;
    if (t + 1 < N) {
      int rown = dir ? (N - 2 - t) : (t + 1);
      if (xvalid) xw_nx = xw[(size_t)(row0 + rown) * 2848 + xcol];
    }

    // dots: s[q] = Whh_row_q . h   (12 independent rows, interleaved butterfly)
    float s[12];
#pragma unroll
    for (int q = 0; q < 12; ++q) {
      float v = wreg[q][0] * hreg[0];
#pragma unroll
      for (int ii = 1; ii < 6; ++ii) v += wreg[q][ii] * hreg[ii];
      s[q] = v;
    }
#pragma unroll
    for (int off = 32; off > 0; off >>= 1) {
#pragma unroll
      for (int q = 0; q < 12; ++q) s[q] += __shfl_xor(s[q], off);
    }

    // gather xw gates of own unit (lane u pulls from lanes 4u..4u+3)
    float x0 = __shfl(xw_cur, 4 * lane + 0);
    float x1 = __shfl(xw_cur, 4 * lane + 1);
    float x2 = __shfl(xw_cur, 4 * lane + 2);
    float x3 = __shfl(xw_cur, 4 * lane + 3);
    float zi, zf, zg, zo;
    if (lane == 1)      { zi = s[4]; zf = s[5]; zg = s[6];  zo = s[7];  }
    else if (lane == 2) { zi = s[8]; zf = s[9]; zg = s[10]; zo = s[11]; }
    else                { zi = s[0]; zf = s[1]; zg = s[2];  zo = s[3];  }

    if (lane < nu) {
      float c = sigm(zf + x1) * c_reg + sigm(zi + x0) * tanhf(zg + x2);
      float h = sigm(zo + x3) * tanhf(c);
      c_reg = c;
      int j = j0 + base_u + lane;
      unsigned long long pk =
          ((unsigned long long)(unsigned)(t + 1) << 32) |
          (unsigned long long)__float_as_uint(h);
      __hip_atomic_store(&exd[(size_t)(t & 1) * 356 + j], pk,
                         __ATOMIC_RELAXED, __HIP_MEMORY_SCOPE_AGENT);
      out[grow * 712 + ocol0 + j] = h;
    }

    // poll the full h(t) straight into registers for the next step
    if (t + 1 < N) {
      unsigned ep = (unsigned)(t + 1);
      unsigned long long* pb = exd + (size_t)(t & 1) * 356;
#pragma unroll
      for (int ii = 0; ii < 6; ++ii) {
        int k = lane + ii * 64;
        if (k < 356) {
          unsigned long long v;
          do {
            v = __hip_atomic_load(&pb[k], __ATOMIC_RELAXED,
                                  __HIP_MEMORY_SCOPE_AGENT);
          } while ((unsigned)(v >> 32) != ep);
          hreg[ii] = __uint_as_float((unsigned)v);
        }
      }
    }
    xw_cur = xw_nx;
  }
}

// ---------------------------------------------------------------------------
// attention: s2[j] = Q[j] . w_q
// ---------------------------------------------------------------------------
__global__ __launch_bounds__(64) void qdot_kernel(
    const float* __restrict__ Q, const float* __restrict__ sim_w, float* __restrict__ s2)
{
  int j = blockIdx.x;
  int lane = threadIdx.x;
  const float* q  = Q + (size_t)j * 712;
  const float* wq = sim_w + 712;
  float s = 0.f;
  for (int k = lane; k < 712; k += 64) s += q[k] * wq[k];
  s = waveSum(s);
  if (lane == 0) s2[j] = s;
}

// ---------------------------------------------------------------------------
// per-context-row attention + qac[0,2136)
// ---------------------------------------------------------------------------
__global__ __launch_bounds__(256) void attn_row_kernel(
    const float* __restrict__ CQ, const float* __restrict__ sim_w,
    const float* __restrict__ s2, float* __restrict__ rowm, float* __restrict__ qac)
{
  int i = blockIdx.x;   // 0..4095
  int tid = threadIdx.x;
  const float* Q = CQ + (size_t)4096 * 712;
  __shared__ float crow[712], cw[712], prow[128], red[256];
  const float* ci = CQ + (size_t)i * 712;

  float s1p = 0.f;
  for (int k = tid; k < 712; k += 256) {
    float v = ci[k];
    crow[k] = v;
    cw[k] = v * sim_w[1424 + k];
    s1p += v * sim_w[k];
  }
  red[tid] = s1p;
  __syncthreads();
  for (int s = 128; s > 0; s >>= 1) { if (tid < s) red[tid] += red[tid + s]; __syncthreads(); }
  float s1 = red[0];

  int lane = tid & 63, wv = tid >> 6;
  for (int j = wv; j < 128; j += 4) {
    const float* qj = Q + (size_t)j * 712;
    float s = 0.f;
    for (int k = lane; k < 712; k += 64) s += cw[k] * qj[k];
    s = waveSum(s);
    if (lane == 0) prow[j] = s1 + s2[j] + s;
  }
  __syncthreads();

  float v = (tid < 128) ? prow[tid] : -1e30f;
  red[tid] = v;
  __syncthreads();
  for (int s = 128; s > 0; s >>= 1) { if (tid < s) red[tid] = fmaxf(red[tid], red[tid + s]); __syncthreads(); }
  float m = red[0];
  __syncthreads();
  float e = (tid < 128) ? __expf(prow[tid] - m) : 0.f;
  red[tid] = e;
  __syncthreads();
  for (int s = 128; s > 0; s >>= 1) { if (tid < s) red[tid] += red[tid + s]; __syncthreads(); }
  float denom = red[0];
  if (tid < 128) prow[tid] = e / denom;
  if (tid == 0) rowm[i] = m;
  __syncthreads();

  size_t qb = (size_t)i * 2848;
  for (int k = tid; k < 712; k += 256) {
    float acc = 0.f;
    for (int j = 0; j < 128; ++j) acc += prow[j] * Q[(size_t)j * 712 + k];
    float cv = crow[k];
    qac[qb + k]        = cv;
    qac[qb + 712 + k]  = acc;
    qac[qb + 1424 + k] = cv * acc;
  }
}

// ---------------------------------------------------------------------------
// softmax over a length-4096 vector (single block)
// ---------------------------------------------------------------------------
__global__ __launch_bounds__(256) void softmax_4096(const float* __restrict__ in,
                                                    float* __restrict__ out)
{
  __shared__ float red[256];
  int tid = threadIdx.x;
  float m = -1e30f;
  for (int i = tid; i < 4096; i += 256) m = fmaxf(m, in[i]);
  red[tid] = m;
  __syncthreads();
  for (int s = 128; s > 0; s >>= 1) { if (tid < s) red[tid] = fmaxf(red[tid], red[tid + s]); __syncthreads(); }
  m = red[0];
  __syncthreads();
  float sum = 0.f;
  for (int i = tid; i < 4096; i += 256) sum += __expf(in[i] - m);
  red[tid] = sum;
  __syncthreads();
  for (int s = 128; s > 0; s >>= 1) { if (tid < s) red[tid] += red[tid + s]; __syncthreads(); }
  float denom = red[0];
  for (int i = tid; i < 4096; i += 256) out[i] = __expf(in[i] - m) / denom;
}

// ---------------------------------------------------------------------------
// q2c[k] = sum_i a[i]*C[i,k]
// ---------------------------------------------------------------------------
__global__ __launch_bounds__(256) void q2c_kernel(
    const float* __restrict__ CQ, const float* __restrict__ rowa, float* __restrict__ q2c)
{
  int k = blockIdx.x * 256 + threadIdx.x;
  if (k < 712) {
    float acc = 0.f;
    for (int i = 0; i < 4096; ++i) acc += rowa[i] * CQ[(size_t)i * 712 + k];
    q2c[k] = acc;
  }
}

__global__ __launch_bounds__(256) void qac_finish_kernel(
    const float* __restrict__ CQ, const float* __restrict__ q2c, float* __restrict__ qac)
{
  int i = blockIdx.x;
  int tid = threadIdx.x;
  for (int k = tid; k < 712; k += 256)
    qac[(size_t)i * 2848 + 2136 + k] = CQ[(size_t)i * 712 + k] * q2c[k];
}

__global__ __launch_bounds__(256) void logits_kernel(
    const float* __restrict__ qac, const float* __restrict__ Mx,
    const float* __restrict__ w, float* __restrict__ logits)
{
  int i = blockIdx.x, tid = threadIdx.x;
  __shared__ float red[256];
  float s = 0.f;
  const float* qr = qac + (size_t)i * 2848;
  for (int k = tid; k < 2848; k += 256) s += qr[k] * w[k];
  const float* mr = Mx + (size_t)i * 712;
  for (int k = tid; k < 712; k += 256) s += mr[k] * w[2848 + k];
  red[tid] = s;
  __syncthreads();
  for (int st = 128; st > 0; st >>= 1) { if (tid < st) red[tid] += red[tid + st]; __syncthreads(); }
  if (tid == 0) logits[i] = red[0];
}

// ---------------------------------------------------------------------------
// host side
// ---------------------------------------------------------------------------
extern "C" void kernel_launch(void* const* d_in, const int* in_sizes, int n_in,
                              void* d_out, int out_size, void* d_ws, size_t ws_size,
                              hipStream_t stream)
{
  const int*   chars_ctx = (const int*)d_in[0];
  const int*   chars_qry = (const int*)d_in[1];
  const float* elmo_ctx  = (const float*)d_in[2];
  const float* elmo_qry  = (const float*)d_in[3];
  const float* char_emb  = (const float*)d_in[4];
  const float* conv_w    = (const float*)d_in[5];
  const float* conv_b    = (const float*)d_in[6];
  const float* hw_plain_w = (const float*)d_in[7];
  const float* hw_plain_b = (const float*)d_in[8];
  const float* hw_gate_w  = (const float*)d_in[9];
  const float* hw_gate_b  = (const float*)d_in[10];
  const float* ctx_Wih   = (const float*)d_in[11];
  const float* ctx_Whh   = (const float*)d_in[12];
  const float* ctx_b     = (const float*)d_in[13];
  const float* sim_w     = (const float*)d_in[14];
  const float* mod1_Wih  = (const float*)d_in[15];
  const float* mod1_Whh  = (const float*)d_in[16];
  const float* mod1_b    = (const float*)d_in[17];
  const float* mod2_Wih  = (const float*)d_in[18];
  const float* mod2_Whh  = (const float*)d_in[19];
  const float* mod2_b    = (const float*)d_in[20];
  const float* pos_Wih   = (const float*)d_in[21];
  const float* pos_Whh   = (const float*)d_in[22];
  const float* pos_b     = (const float*)d_in[23];
  const float* pos1_w    = (const float*)d_in[24];
  const float* pos2_w    = (const float*)d_in[25];
  const float* h0_ctx_c  = (const float*)d_in[26];
  const float* h0_ctx_q  = (const float*)d_in[27];
  const float* h0_mod    = (const float*)d_in[28];
  const float* h0_pos    = (const float*)d_in[29];
  float* outp = (float*)d_out;

  float* ws = (float*)d_ws;
  size_t off = 0;
  auto alloc = [&](size_t n) { float* p = ws + off; off += n; return p; };
  float* x_all  = alloc(4224ull * 356);
  float* gbuf   = alloc(4224ull * 356);
  float* pbuf   = alloc(4224ull * 356);
  float* xw_all = alloc(4224ull * 2848);
  float* CQ     = alloc(4224ull * 712);
  float* M1     = alloc(4096ull * 712);
  float* Mm     = alloc(4096ull * 712);
  float* M2     = alloc(4096ull * 712);
  float* qac    = alloc(4096ull * 2848);
  float* s2v    = alloc(128);
  float* rowm   = alloc(4096);
  float* rowa   = alloc(4096);
  float* q2cv   = alloc(1024);
  float* logits = alloc(8192);
  off = (off + 1) & ~(size_t)1;                    // 8B align
  unsigned long long* exbuf = (unsigned long long*)(ws + off);
  // 5 scans x [2 dirs][2 parity][356] u64 — poisoned 0xAA by the harness;
  // 0xAAAAAAAA never equals any epoch t+1 <= 4096, so no memset needed.
  off += 5ull * 1424 * 2;

  auto cdiv = [](int a, int b) { return (a + b - 1) / b; };

  // 1) char CNN + elmo concat
  cnn_embed_kernel<<<4224, 128, 0, stream>>>(chars_ctx, chars_qry, elmo_ctx, elmo_qry,
                                             char_emb, conv_w, conv_b, x_all);

  // 2) highway x2
  for (int l = 0; l < 2; ++l) {
    gemm_abt<<<dim3(cdiv(356, BNT), cdiv(4224, BMT)), 256, 0, stream>>>(
        x_all, hw_gate_w + (size_t)l * 356 * 356, hw_gate_b + l * 356, gbuf, 4224, 356, 356);
    gemm_abt<<<dim3(cdiv(356, BNT), cdiv(4224, BMT)), 256, 0, stream>>>(
        x_all, hw_plain_w + (size_t)l * 356 * 356, hw_plain_b + l * 356, pbuf, 4224, 356, 356);
    highway_combine<<<cdiv(4224 * 356, 256), 256, 0, stream>>>(x_all, gbuf, pbuf, 4224 * 356);
  }

  // 3) ctx BiLSTM — ctx (4096 steps) and qry (128 steps) ride one dispatch
  gemm_abt<<<dim3(cdiv(2848, BNT), cdiv(4224, BMT)), 256, 0, stream>>>(
      x_all, ctx_Wih, ctx_b, xw_all, 4224, 2848, 356);
  lstm_scan_kernel<<<4 * NWG, 512, 0, stream>>>(xw_all, ctx_Whh, h0_ctx_c, CQ, 0, 4096,
                                                exbuf + 0ull * 1424,
                                                h0_ctx_q, 4096, 128,
                                                exbuf + 1ull * 1424);

  // 4) attention
  qdot_kernel<<<128, 64, 0, stream>>>(CQ + 4096ull * 712, sim_w, s2v);
  attn_row_kernel<<<4096, 256, 0, stream>>>(CQ, sim_w, s2v, rowm, qac);
  softmax_4096<<<1, 256, 0, stream>>>(rowm, rowa);
  q2c_kernel<<<cdiv(712, 256), 256, 0, stream>>>(CQ, rowa, q2cv);
  qac_finish_kernel<<<4096, 256, 0, stream>>>(CQ, q2cv, qac);

  // 5) mod1 BiLSTM (input 2848)
  gemm_abt<<<dim3(cdiv(2848, BNT), cdiv(4096, BMT)), 256, 0, stream>>>(
      qac, mod1_Wih, mod1_b, xw_all, 4096, 2848, 2848);
  lstm_scan_kernel<<<2 * NWG, 512, 0, stream>>>(xw_all, mod1_Whh, h0_mod, M1, 0, 4096,
                                                exbuf + 2ull * 1424,
                                                nullptr, 0, 0, nullptr);

  // 6) mod2 BiLSTM (input 712)
  gemm_abt<<<dim3(cdiv(2848, BNT), cdiv(4096, BMT)), 256, 0, stream>>>(
      M1, mod2_Wih, mod2_b, xw_all, 4096, 2848, 712);
  lstm_scan_kernel<<<2 * NWG, 512, 0, stream>>>(xw_all, mod2_Whh, h0_mod + 712, Mm, 0, 4096,
                                                exbuf + 3ull * 1424,
                                                nullptr, 0, 0, nullptr);

  // 7) pos1
  logits_kernel<<<4096, 256, 0, stream>>>(qac, Mm, pos1_w, logits);
  softmax_4096<<<1, 256, 0, stream>>>(logits, outp);

  // 8) pos BiLSTM then pos2
  gemm_abt<<<dim3(cdiv(2848, BNT), cdiv(4096, BMT)), 256, 0, stream>>>(
      Mm, pos_Wih, pos_b, xw_all, 4096, 2848, 712);
  lstm_scan_kernel<<<2 * NWG, 512, 0, stream>>>(xw_all, pos_Whh, h0_pos, M2, 0, 4096,
                                                exbuf + 4ull * 1424,
                                                nullptr, 0, 0, nullptr);
  logits_kernel<<<4096, 256, 0, stream>>>(qac, M2, pos2_w, logits + 4096);
  softmax_4096<<<1, 256, 0, stream>>>(logits + 4096, outp + 4096);

  (void)in_sizes; (void)n_in; (void)out_size; (void)ws_size;
}

// Round 2
// 102247.961 us; speedup vs baseline: 1.1055x; 1.1055x over previous
//
#include <hip/hip_runtime.h>
#include <math.h>

// ---------------------------------------------------------------------------
// helpers
// ---------------------------------------------------------------------------
__device__ __forceinline__ float sigm(float x) { return 1.0f / (1.0f + __expf(-x)); }

__device__ __forceinline__ float waveSum(float v) {
#pragma unroll
  for (int off = 32; off > 0; off >>= 1) v += __shfl_xor(v, off);
  return v;
}

// ---------------------------------------------------------------------------
// char CNN + elmo concat  -> x_all (4224 x 356)
// ---------------------------------------------------------------------------
__global__ __launch_bounds__(128) void cnn_embed_kernel(
    const int* __restrict__ chars_ctx, const int* __restrict__ chars_qry,
    const float* __restrict__ elmo_ctx, const float* __restrict__ elmo_qry,
    const float* __restrict__ char_emb, const float* __restrict__ conv_w,
    const float* __restrict__ conv_b, float* __restrict__ x_all)
{
  int n = blockIdx.x;
  const int*   chars = (n < 4096) ? (chars_ctx + n * 16) : (chars_qry + (n - 4096) * 16);
  const float* elmo  = (n < 4096) ? (elmo_ctx + (size_t)n * 256)
                                  : (elmo_qry + (size_t)(n - 4096) * 256);
  __shared__ float xl[1600];   // [emb_dim=100][pos=16]
  __shared__ int   cidx[16];
  int tid = threadIdx.x;
  if (tid < 16) cidx[tid] = chars[tid];
  __syncthreads();
  for (int e = tid; e < 1600; e += 128) {
    int i = e >> 4, p = e & 15;
    xl[e] = char_emb[cidx[p] * 100 + i];
  }
  __syncthreads();
  if (tid < 100) {
    int o = tid;
    float acc[16];
#pragma unroll
    for (int p = 0; p < 16; ++p) acc[p] = 0.f;
    const float* wo = conv_w + o * 500;
    for (int i = 0; i < 100; ++i) {
      const float* xi = xl + i * 16;
#pragma unroll
      for (int k = 0; k < 5; ++k) {
        float w = wo[i * 5 + k];
#pragma unroll
        for (int p = 0; p < 16; ++p) {
          int src = p + k - 2;
          if (src >= 0 && src < 16) acc[p] += w * xi[src];
        }
      }
    }
    float m = acc[0];
#pragma unroll
    for (int p = 1; p < 16; ++p) m = fmaxf(m, acc[p]);
    x_all[(size_t)n * 356 + o] = m + conv_b[o];
  }
  for (int j = tid; j < 256; j += 128)
    x_all[(size_t)n * 356 + 100 + j] = elmo[j];
}

// ---------------------------------------------------------------------------
// generic fp32 GEMM:  C[M,N] = A[M,K] @ B[N,K]^T + bias[N]
// ---------------------------------------------------------------------------
#define BMT 64
#define BNT 64
#define BKT 16

__global__ __launch_bounds__(256) void gemm_abt(
    const float* __restrict__ A, const float* __restrict__ B,
    const float* __restrict__ bias, float* __restrict__ C,
    int M, int N, int K)
{
  __shared__ float As[BKT][BMT + 4];
  __shared__ float Bs[BKT][BNT + 4];
  int tid = threadIdx.x;
  int bm = blockIdx.y * BMT, bn = blockIdx.x * BNT;
  int tm = (tid >> 4) << 2;
  int tn = (tid & 15) << 2;
  float acc[4][4];
#pragma unroll
  for (int i = 0; i < 4; ++i)
#pragma unroll
    for (int j = 0; j < 4; ++j) acc[i][j] = 0.f;

  for (int k0 = 0; k0 < K; k0 += BKT) {
    for (int e = tid; e < BMT * BKT; e += 256) {
      int m = e >> 4, kk = e & 15;
      int gm = bm + m, gk = k0 + kk;
      As[kk][m] = (gm < M && gk < K) ? A[(size_t)gm * K + gk] : 0.f;
    }
    for (int e = tid; e < BNT * BKT; e += 256) {
      int nn = e >> 4, kk = e & 15;
      int gn = bn + nn, gk = k0 + kk;
      Bs[kk][nn] = (gn < N && gk < K) ? B[(size_t)gn * K + gk] : 0.f;
    }
    __syncthreads();
#pragma unroll
    for (int kk = 0; kk < BKT; ++kk) {
      float a[4], b[4];
#pragma unroll
      for (int i = 0; i < 4; ++i) a[i] = As[kk][tm + i];
#pragma unroll
      for (int j = 0; j < 4; ++j) b[j] = Bs[kk][tn + j];
#pragma unroll
      for (int i = 0; i < 4; ++i)
#pragma unroll
        for (int j = 0; j < 4; ++j) acc[i][j] += a[i] * b[j];
    }
    __syncthreads();
  }
#pragma unroll
  for (int i = 0; i < 4; ++i) {
    int gm = bm + tm + i;
    if (gm >= M) continue;
#pragma unroll
    for (int j = 0; j < 4; ++j) {
      int gn = bn + tn + j;
      if (gn < N) {
        float v = acc[i][j];
        if (bias) v += bias[gn];
        C[(size_t)gm * N + gn] = v;
      }
    }
  }
}

// ---------------------------------------------------------------------------
// highway combine
// ---------------------------------------------------------------------------
__global__ void highway_combine(float* __restrict__ x, const float* __restrict__ g,
                                const float* __restrict__ p, int total)
{
  int i = blockIdx.x * blockDim.x + threadIdx.x;
  if (i < total) {
    float gg = sigm(g[i]);
    float pp = fmaxf(p[i], 0.f);
    x[i] = gg * pp + (1.f - gg) * x[i];
  }
}

// ---------------------------------------------------------------------------
// persistent BiLSTM scan kernel, v4: wave-autonomous with BATCHED poll.
//
// v3 post-mortem: six *serialized* spin loops (one per 64-lane chunk of h)
// put 6 dependent LLC round trips on every step's critical path, and the
// __shfl xw-gathers added 8.1M ds-crossbar conflicts. v4 keeps the
// zero-barrier structure but:
//   - polls all 6 chunks as ONE batch (6 independent loads -> one vmcnt
//     wait -> check all epochs -> retry whole batch). Common case is a
//     single LLC round trip for the full h(t).
//   - owning lane u loads its unit's 4 xw gate values directly from
//     global (no cross-lane gather shuffles).
// Numerics identical. The epoch/parity lap-protection invariant is
// unchanged: every live wave polls the full h each step, so no publisher
// can advance 2 steps ahead of any reader; zero-unit waves exit early.
// ---------------------------------------------------------------------------
#define NWG 16
#define SLICE 23   // 16*23 = 368 >= 356
#define NU 3       // units per wave (8 waves * 3 = 24 >= 23)

__global__ __launch_bounds__(512, 1) void lstm_scan_kernel(
    const float* __restrict__ xw, const float* __restrict__ whh,
    const float* __restrict__ h0, float* __restrict__ out,
    int row0, int N, unsigned long long* exbuf,
    const float* __restrict__ h0b, int row0b, int Nb,
    unsigned long long* exbufb)
{
  int bid = blockIdx.x;
  if (bid >= 2 * NWG) {          // optional second problem
    bid -= 2 * NWG;
    h0 = h0b; row0 = row0b; N = Nb; exbuf = exbufb;
    if (N <= 0) return;
  }
  const int tid  = threadIdx.x;
  const int dir  = bid & 1;
  const int wg   = bid >> 1;
  const int lane = tid & 63;
  const int wv   = tid >> 6;          // 0..7
  const int j0   = wg * SLICE;
  const int base_u = wv * NU;
  const float* whh_d = whh + (size_t)dir * 1424 * 356;
  const float* h0_d  = h0 + dir * 356;
  const int xcol0 = dir * 1424;
  const int ocol0 = dir * 356;
  unsigned long long* exd = exbuf + (size_t)dir * 712;   // [parity][356]

  // number of valid units owned by this wave (prefix-valid)
  int nu = 0;
#pragma unroll
  for (int u = 0; u < NU; ++u) {
    int uu = base_u + u;
    if (uu < SLICE && (j0 + uu) < 356) nu = u + 1;
  }
  if (nu == 0) return;   // owns nothing, publishes nothing -> must not poll

  // Whh rows -> registers. Row q = u*4 + g covers gate g of unit j0+base_u+u.
  float wreg[12][6];
#pragma unroll
  for (int q = 0; q < 12; ++q) {
    int u = q >> 2, g = q & 3;
    bool v = (u < nu);
    int j = j0 + base_u + (v ? u : 0);
    const float* wrow = whh_d + (size_t)(g * 356 + j) * 356;
#pragma unroll
    for (int ii = 0; ii < 6; ++ii) {
      int k = lane + ii * 64;
      wreg[q][ii] = (v && k < 356) ? wrow[k] : 0.f;
    }
  }

  // h state in registers: hreg[ii] = h[lane + 64*ii]
  float hreg[6];
#pragma unroll
  for (int ii = 0; ii < 6; ++ii) {
    int k = lane + ii * 64;
    hreg[ii] = (k < 356) ? h0_d[k] : 0.f;
  }

  // lane u (u < nu) owns unit ju: cell state + its 4 xw gate streams
  const bool uown = (lane < nu);
  const int  ju   = j0 + base_u + (uown ? lane : 0);
  float c_reg = uown ? h0_d[ju] : 0.f;
  const size_t xoff = (size_t)(xcol0 + ju);

  float xw_cur[4];
  {
    int row = dir ? (N - 1) : 0;
    size_t rb = (size_t)(row0 + row) * 2848 + xoff;
#pragma unroll
    for (int g = 0; g < 4; ++g) xw_cur[g] = uown ? xw[rb + g * 356] : 0.f;
  }

  for (int t = 0; t < N; ++t) {
    int row = dir ? (N - 1 - t) : t;
    size_t grow = (size_t)(row0 + row);

    // issue next-step xw prefetch first (covered by this step's compute+poll)
    float xw_nx[4];
#pragma unroll
    for (int g = 0; g < 4; ++g) xw_nx[g] = 0.f;
    if (t + 1 < N) {
      int rown = dir ? (N - 2 - t) : (t + 1);
      size_t rb = (size_t)(row0 + rown) * 2848 + xoff;
#pragma unroll
      for (int g = 0; g < 4; ++g) xw_nx[g] = uown ? xw[rb + g * 356] : 0.f;
    }

    // dots: s[q] = Whh_row_q . h   (12 independent rows, interleaved butterfly)
    float s[12];
#pragma unroll
    for (int q = 0; q < 12; ++q) {
      float v = wreg[q][0] * hreg[0];
#pragma unroll
      for (int ii = 1; ii < 6; ++ii) v += wreg[q][ii] * hreg[ii];
      s[q] = v;
    }
#pragma unroll
    for (int off = 32; off > 0; off >>= 1) {
#pragma unroll
      for (int q = 0; q < 12; ++q) s[q] += __shfl_xor(s[q], off);
    }

    // gate math + publish: lane u uses s[4u .. 4u+3] and its own xw gates
    float zi, zf, zg, zo;
    if (lane == 1)      { zi = s[4]; zf = s[5]; zg = s[6];  zo = s[7];  }
    else if (lane == 2) { zi = s[8]; zf = s[9]; zg = s[10]; zo = s[11]; }
    else                { zi = s[0]; zf = s[1]; zg = s[2];  zo = s[3];  }

    if (uown) {
      float c = sigm(zf + xw_cur[1]) * c_reg + sigm(zi + xw_cur[0]) * tanhf(zg + xw_cur[2]);
      float h = sigm(zo + xw_cur[3]) * tanhf(c);
      c_reg = c;
      unsigned long long pk =
          ((unsigned long long)(unsigned)(t + 1) << 32) |
          (unsigned long long)__float_as_uint(h);
      __hip_atomic_store(&exd[(size_t)(t & 1) * 356 + ju], pk,
                         __ATOMIC_RELAXED, __HIP_MEMORY_SCOPE_AGENT);
      out[grow * 712 + ocol0 + ju] = h;
    }

    // batched poll: issue all 6 chunk loads, wait once, check all epochs.
    if (t + 1 < N) {
      unsigned ep = (unsigned)(t + 1);
      unsigned long long* pb = exd + (size_t)(t & 1) * 356;
      unsigned long long v[6];
      for (;;) {
#pragma unroll
        for (int ii = 0; ii < 6; ++ii) {
          int k = lane + ii * 64;
          if (k < 356)
            v[ii] = __hip_atomic_load(&pb[k], __ATOMIC_RELAXED,
                                      __HIP_MEMORY_SCOPE_AGENT);
          else
            v[ii] = (unsigned long long)ep << 32;
        }
        bool ok = true;
#pragma unroll
        for (int ii = 0; ii < 6; ++ii)
          ok &= ((unsigned)(v[ii] >> 32) == ep);
        if (ok) break;
      }
#pragma unroll
      for (int ii = 0; ii < 6; ++ii) {
        int k = lane + ii * 64;
        if (k < 356) hreg[ii] = __uint_as_float((unsigned)v[ii]);
      }
    }
#pragma unroll
    for (int g = 0; g < 4; ++g) xw_cur[g] = xw_nx[g];
  }
}

// ---------------------------------------------------------------------------
// attention: s2[j] = Q[j] . w_q
// ---------------------------------------------------------------------------
__global__ __launch_bounds__(64) void qdot_kernel(
    const float* __restrict__ Q, const float* __restrict__ sim_w, float* __restrict__ s2)
{
  int j = blockIdx.x;
  int lane = threadIdx.x;
  const float* q  = Q + (size_t)j * 712;
  const float* wq = sim_w + 712;
  float s = 0.f;
  for (int k = lane; k < 712; k += 64) s += q[k] * wq[k];
  s = waveSum(s);
  if (lane == 0) s2[j] = s;
}

// ---------------------------------------------------------------------------
// per-context-row attention + qac[0,2136)
// ---------------------------------------------------------------------------
__global__ __launch_bounds__(256) void attn_row_kernel(
    const float* __restrict__ CQ, const float* __restrict__ sim_w,
    const float* __restrict__ s2, float* __restrict__ rowm, float* __restrict__ qac)
{
  int i = blockIdx.x;   // 0..4095
  int tid = threadIdx.x;
  const float* Q = CQ + (size_t)4096 * 712;
  __shared__ float crow[712], cw[712], prow[128], red[256];
  const float* ci = CQ + (size_t)i * 712;

  float s1p = 0.f;
  for (int k = tid; k < 712; k += 256) {
    float v = ci[k];
    crow[k] = v;
    cw[k] = v * sim_w[1424 + k];
    s1p += v * sim_w[k];
  }
  red[tid] = s1p;
  __syncthreads();
  for (int s = 128; s > 0; s >>= 1) { if (tid < s) red[tid] += red[tid + s]; __syncthreads(); }
  float s1 = red[0];

  int lane = tid & 63, wv = tid >> 6;
  for (int j = wv; j < 128; j += 4) {
    const float* qj = Q + (size_t)j * 712;
    float s = 0.f;
    for (int k = lane; k < 712; k += 64) s += cw[k] * qj[k];
    s = waveSum(s);
    if (lane == 0) prow[j] = s1 + s2[j] + s;
  }
  __syncthreads();

  float v = (tid < 128) ? prow[tid] : -1e30f;
  red[tid] = v;
  __syncthreads();
  for (int s = 128; s > 0; s >>= 1) { if (tid < s) red[tid] = fmaxf(red[tid], red[tid + s]); __syncthreads(); }
  float m = red[0];
  __syncthreads();
  float e = (tid < 128) ? __expf(prow[tid] - m) : 0.f;
  red[tid] = e;
  __syncthreads();
  for (int s = 128; s > 0; s >>= 1) { if (tid < s) red[tid] += red[tid + s]; __syncthreads(); }
  float denom = red[0];
  if (tid < 128) prow[tid] = e / denom;
  if (tid == 0) rowm[i] = m;
  __syncthreads();

  size_t qb = (size_t)i * 2848;
  for (int k = tid; k < 712; k += 256) {
    float acc = 0.f;
    for (int j = 0; j < 128; ++j) acc += prow[j] * Q[(size_t)j * 712 + k];
    float cv = crow[k];
    qac[qb + k]        = cv;
    qac[qb + 712 + k]  = acc;
    qac[qb + 1424 + k] = cv * acc;
  }
}

// ---------------------------------------------------------------------------
// softmax over a length-4096 vector (single block)
// ---------------------------------------------------------------------------
__global__ __launch_bounds__(256) void softmax_4096(const float* __restrict__ in,
                                                    float* __restrict__ out)
{
  __shared__ float red[256];
  int tid = threadIdx.x;
  float m = -1e30f;
  for (int i = tid; i < 4096; i += 256) m = fmaxf(m, in[i]);
  red[tid] = m;
  __syncthreads();
  for (int s = 128; s > 0; s >>= 1) { if (tid < s) red[tid] = fmaxf(red[tid], red[tid + s]); __syncthreads(); }
  m = red[0];
  __syncthreads();
  float sum = 0.f;
  for (int i = tid; i < 4096; i += 256) sum += __expf(in[i] - m);
  red[tid] = sum;
  __syncthreads();
  for (int s = 128; s > 0; s >>= 1) { if (tid < s) red[tid] += red[tid + s]; __syncthreads(); }
  float denom = red[0];
  for (int i = tid; i < 4096; i += 256) out[i] = __expf(in[i] - m) / denom;
}

// ---------------------------------------------------------------------------
// q2c[k] = sum_i a[i]*C[i,k]
// ---------------------------------------------------------------------------
__global__ __launch_bounds__(256) void q2c_kernel(
    const float* __restrict__ CQ, const float* __restrict__ rowa, float* __restrict__ q2c)
{
  int k = blockIdx.x * 256 + threadIdx.x;
  if (k < 712) {
    float acc = 0.f;
    for (int i = 0; i < 4096; ++i) acc += rowa[i] * CQ[(size_t)i * 712 + k];
    q2c[k] = acc;
  }
}

__global__ __launch_bounds__(256) void qac_finish_kernel(
    const float* __restrict__ CQ, const float* __restrict__ q2c, float* __restrict__ qac)
{
  int i = blockIdx.x;
  int tid = threadIdx.x;
  for (int k = tid; k < 712; k += 256)
    qac[(size_t)i * 2848 + 2136 + k] = CQ[(size_t)i * 712 + k] * q2c[k];
}

__global__ __launch_bounds__(256) void logits_kernel(
    const float* __restrict__ qac, const float* __restrict__ Mx,
    const float* __restrict__ w, float* __restrict__ logits)
{
  int i = blockIdx.x, tid = threadIdx.x;
  __shared__ float red[256];
  float s = 0.f;
  const float* qr = qac + (size_t)i * 2848;
  for (int k = tid; k < 2848; k += 256) s += qr[k] * w[k];
  const float* mr = Mx + (size_t)i * 712;
  for (int k = tid; k < 712; k += 256) s += mr[k] * w[2848 + k];
  red[tid] = s;
  __syncthreads();
  for (int st = 128; st > 0; st >>= 1) { if (tid < st) red[tid] += red[tid + st]; __syncthreads(); }
  if (tid == 0) logits[i] = red[0];
}

// ---------------------------------------------------------------------------
// host side
// ---------------------------------------------------------------------------
extern "C" void kernel_launch(void* const* d_in, const int* in_sizes, int n_in,
                              void* d_out, int out_size, void* d_ws, size_t ws_size,
                              hipStream_t stream)
{
  const int*   chars_ctx = (const int*)d_in[0];
  const int*   chars_qry = (const int*)d_in[1];
  const float* elmo_ctx  = (const float*)d_in[2];
  const float* elmo_qry  = (const float*)d_in[3];
  const float* char_emb  = (const float*)d_in[4];
  const float* conv_w    = (const float*)d_in[5];
  const float* conv_b    = (const float*)d_in[6];
  const float* hw_plain_w = (const float*)d_in[7];
  const float* hw_plain_b = (const float*)d_in[8];
  const float* hw_gate_w  = (const float*)d_in[9];
  const float* hw_gate_b  = (const float*)d_in[10];
  const float* ctx_Wih   = (const float*)d_in[11];
  const float* ctx_Whh   = (const float*)d_in[12];
  const float* ctx_b     = (const float*)d_in[13];
  const float* sim_w     = (const float*)d_in[14];
  const float* mod1_Wih  = (const float*)d_in[15];
  const float* mod1_Whh  = (const float*)d_in[16];
  const float* mod1_b    = (const float*)d_in[17];
  const float* mod2_Wih  = (const float*)d_in[18];
  const float* mod2_Whh  = (const float*)d_in[19];
  const float* mod2_b    = (const float*)d_in[20];
  const float* pos_Wih   = (const float*)d_in[21];
  const float* pos_Whh   = (const float*)d_in[22];
  const float* pos_b     = (const float*)d_in[23];
  const float* pos1_w    = (const float*)d_in[24];
  const float* pos2_w    = (const float*)d_in[25];
  const float* h0_ctx_c  = (const float*)d_in[26];
  const float* h0_ctx_q  = (const float*)d_in[27];
  const float* h0_mod    = (const float*)d_in[28];
  const float* h0_pos    = (const float*)d_in[29];
  float* outp = (float*)d_out;

  float* ws = (float*)d_ws;
  size_t off = 0;
  auto alloc = [&](size_t n) { float* p = ws + off; off += n; return p; };
  float* x_all  = alloc(4224ull * 356);
  float* gbuf   = alloc(4224ull * 356);
  float* pbuf   = alloc(4224ull * 356);
  float* xw_all = alloc(4224ull * 2848);
  float* CQ     = alloc(4224ull * 712);
  float* M1     = alloc(4096ull * 712);
  float* Mm     = alloc(4096ull * 712);
  float* M2     = alloc(4096ull * 712);
  float* qac    = alloc(4096ull * 2848);
  float* s2v    = alloc(128);
  float* rowm   = alloc(4096);
  float* rowa   = alloc(4096);
  float* q2cv   = alloc(1024);
  float* logits = alloc(8192);
  off = (off + 1) & ~(size_t)1;                    // 8B align
  unsigned long long* exbuf = (unsigned long long*)(ws + off);
  // 5 scans x [2 dirs][2 parity][356] u64 — poisoned 0xAA by the harness;
  // 0xAAAAAAAA never equals any epoch t+1 <= 4096, so no memset needed.
  off += 5ull * 1424 * 2;

  auto cdiv = [](int a, int b) { return (a + b - 1) / b; };

  // 1) char CNN + elmo concat
  cnn_embed_kernel<<<4224, 128, 0, stream>>>(chars_ctx, chars_qry, elmo_ctx, elmo_qry,
                                             char_emb, conv_w, conv_b, x_all);

  // 2) highway x2
  for (int l = 0; l < 2; ++l) {
    gemm_abt<<<dim3(cdiv(356, BNT), cdiv(4224, BMT)), 256, 0, stream>>>(
        x_all, hw_gate_w + (size_t)l * 356 * 356, hw_gate_b + l * 356, gbuf, 4224, 356, 356);
    gemm_abt<<<dim3(cdiv(356, BNT), cdiv(4224, BMT)), 256, 0, stream>>>(
        x_all, hw_plain_w + (size_t)l * 356 * 356, hw_plain_b + l * 356, pbuf, 4224, 356, 356);
    highway_combine<<<cdiv(4224 * 356, 256), 256, 0, stream>>>(x_all, gbuf, pbuf, 4224 * 356);
  }

  // 3) ctx BiLSTM — ctx (4096 steps) and qry (128 steps) ride one dispatch
  gemm_abt<<<dim3(cdiv(2848, BNT), cdiv(4224, BMT)), 256, 0, stream>>>(
      x_all, ctx_Wih, ctx_b, xw_all, 4224, 2848, 356);
  lstm_scan_kernel<<<4 * NWG, 512, 0, stream>>>(xw_all, ctx_Whh, h0_ctx_c, CQ, 0, 4096,
                                                exbuf + 0ull * 1424,
                                                h0_ctx_q, 4096, 128,
                                                exbuf + 1ull * 1424);

  // 4) attention
  qdot_kernel<<<128, 64, 0, stream>>>(CQ + 4096ull * 712, sim_w, s2v);
  attn_row_kernel<<<4096, 256, 0, stream>>>(CQ, sim_w, s2v, rowm, qac);
  softmax_4096<<<1, 256, 0, stream>>>(rowm, rowa);
  q2c_kernel<<<cdiv(712, 256), 256, 0, stream>>>(CQ, rowa, q2cv);
  qac_finish_kernel<<<4096, 256, 0, stream>>>(CQ, q2cv, qac);

  // 5) mod1 BiLSTM (input 2848)
  gemm_abt<<<dim3(cdiv(2848, BNT), cdiv(4096, BMT)), 256, 0, stream>>>(
      qac, mod1_Wih, mod1_b, xw_all, 4096, 2848, 2848);
  lstm_scan_kernel<<<2 * NWG, 512, 0, stream>>>(xw_all, mod1_Whh, h0_mod, M1, 0, 4096,
                                                exbuf + 2ull * 1424,
                                                nullptr, 0, 0, nullptr);

  // 6) mod2 BiLSTM (input 712)
  gemm_abt<<<dim3(cdiv(2848, BNT), cdiv(4096, BMT)), 256, 0, stream>>>(
      M1, mod2_Wih, mod2_b, xw_all, 4096, 2848, 712);
  lstm_scan_kernel<<<2 * NWG, 512, 0, stream>>>(xw_all, mod2_Whh, h0_mod + 712, Mm, 0, 4096,
                                                exbuf + 3ull * 1424,
                                                nullptr, 0, 0, nullptr);

  // 7) pos1
  logits_kernel<<<4096, 256, 0, stream>>>(qac, Mm, pos1_w, logits);
  softmax_4096<<<1, 256, 0, stream>>>(logits, outp);

  // 8) pos BiLSTM then pos2
  gemm_abt<<<dim3(cdiv(2848, BNT), cdiv(4096, BMT)), 256, 0, stream>>>(
      Mm, pos_Wih, pos_b, xw_all, 4096, 2848, 712);
  lstm_scan_kernel<<<2 * NWG, 512, 0, stream>>>(xw_all, pos_Whh, h0_pos, M2, 0, 4096,
                                                exbuf + 4ull * 1424,
                                                nullptr, 0, 0, nullptr);
  logits_kernel<<<4096, 256, 0, stream>>>(qac, M2, pos2_w, logits + 4096);
  softmax_4096<<<1, 256, 0, stream>>>(logits + 4096, outp + 4096);

  (void)in_sizes; (void)n_in; (void)out_size; (void)ws_size;
}

// Round 3
// 84160.577 us; speedup vs baseline: 1.3431x; 1.2149x over previous
//
#include <hip/hip_runtime.h>
#include <math.h>

// ---------------------------------------------------------------------------
// helpers
// ---------------------------------------------------------------------------
__device__ __forceinline__ float sigm(float x) { return 1.0f / (1.0f + __expf(-x)); }

__device__ __forceinline__ float waveSum(float v) {
#pragma unroll
  for (int off = 32; off > 0; off >>= 1) v += __shfl_xor(v, off);
  return v;
}

// ---------------------------------------------------------------------------
// char CNN + elmo concat  -> x_all (4224 x 356)
// ---------------------------------------------------------------------------
__global__ __launch_bounds__(128) void cnn_embed_kernel(
    const int* __restrict__ chars_ctx, const int* __restrict__ chars_qry,
    const float* __restrict__ elmo_ctx, const float* __restrict__ elmo_qry,
    const float* __restrict__ char_emb, const float* __restrict__ conv_w,
    const float* __restrict__ conv_b, float* __restrict__ x_all)
{
  int n = blockIdx.x;
  const int*   chars = (n < 4096) ? (chars_ctx + n * 16) : (chars_qry + (n - 4096) * 16);
  const float* elmo  = (n < 4096) ? (elmo_ctx + (size_t)n * 256)
                                  : (elmo_qry + (size_t)(n - 4096) * 256);
  __shared__ float xl[1600];   // [emb_dim=100][pos=16]
  __shared__ int   cidx[16];
  int tid = threadIdx.x;
  if (tid < 16) cidx[tid] = chars[tid];
  __syncthreads();
  for (int e = tid; e < 1600; e += 128) {
    int i = e >> 4, p = e & 15;
    xl[e] = char_emb[cidx[p] * 100 + i];
  }
  __syncthreads();
  if (tid < 100) {
    int o = tid;
    float acc[16];
#pragma unroll
    for (int p = 0; p < 16; ++p) acc[p] = 0.f;
    const float* wo = conv_w + o * 500;
    for (int i = 0; i < 100; ++i) {
      const float* xi = xl + i * 16;
#pragma unroll
      for (int k = 0; k < 5; ++k) {
        float w = wo[i * 5 + k];
#pragma unroll
        for (int p = 0; p < 16; ++p) {
          int src = p + k - 2;
          if (src >= 0 && src < 16) acc[p] += w * xi[src];
        }
      }
    }
    float m = acc[0];
#pragma unroll
    for (int p = 1; p < 16; ++p) m = fmaxf(m, acc[p]);
    x_all[(size_t)n * 356 + o] = m + conv_b[o];
  }
  for (int j = tid; j < 256; j += 128)
    x_all[(size_t)n * 356 + 100 + j] = elmo[j];
}

// ---------------------------------------------------------------------------
// generic fp32 GEMM:  C[M,N] = A[M,K] @ B[N,K]^T + bias[N]
// ---------------------------------------------------------------------------
#define BMT 64
#define BNT 64
#define BKT 16

__global__ __launch_bounds__(256) void gemm_abt(
    const float* __restrict__ A, const float* __restrict__ B,
    const float* __restrict__ bias, float* __restrict__ C,
    int M, int N, int K)
{
  __shared__ float As[BKT][BMT + 4];
  __shared__ float Bs[BKT][BNT + 4];
  int tid = threadIdx.x;
  int bm = blockIdx.y * BMT, bn = blockIdx.x * BNT;
  int tm = (tid >> 4) << 2;
  int tn = (tid & 15) << 2;
  float acc[4][4];
#pragma unroll
  for (int i = 0; i < 4; ++i)
#pragma unroll
    for (int j = 0; j < 4; ++j) acc[i][j] = 0.f;

  for (int k0 = 0; k0 < K; k0 += BKT) {
    for (int e = tid; e < BMT * BKT; e += 256) {
      int m = e >> 4, kk = e & 15;
      int gm = bm + m, gk = k0 + kk;
      As[kk][m] = (gm < M && gk < K) ? A[(size_t)gm * K + gk] : 0.f;
    }
    for (int e = tid; e < BNT * BKT; e += 256) {
      int nn = e >> 4, kk = e & 15;
      int gn = bn + nn, gk = k0 + kk;
      Bs[kk][nn] = (gn < N && gk < K) ? B[(size_t)gn * K + gk] : 0.f;
    }
    __syncthreads();
#pragma unroll
    for (int kk = 0; kk < BKT; ++kk) {
      float a[4], b[4];
#pragma unroll
      for (int i = 0; i < 4; ++i) a[i] = As[kk][tm + i];
#pragma unroll
      for (int j = 0; j < 4; ++j) b[j] = Bs[kk][tn + j];
#pragma unroll
      for (int i = 0; i < 4; ++i)
#pragma unroll
        for (int j = 0; j < 4; ++j) acc[i][j] += a[i] * b[j];
    }
    __syncthreads();
  }
#pragma unroll
  for (int i = 0; i < 4; ++i) {
    int gm = bm + tm + i;
    if (gm >= M) continue;
#pragma unroll
    for (int j = 0; j < 4; ++j) {
      int gn = bn + tn + j;
      if (gn < N) {
        float v = acc[i][j];
        if (bias) v += bias[gn];
        C[(size_t)gm * N + gn] = v;
      }
    }
  }
}

// ---------------------------------------------------------------------------
// highway combine
// ---------------------------------------------------------------------------
__global__ void highway_combine(float* __restrict__ x, const float* __restrict__ g,
                                const float* __restrict__ p, int total)
{
  int i = blockIdx.x * blockDim.x + threadIdx.x;
  if (i < total) {
    float gg = sigm(g[i]);
    float pp = fmaxf(p[i], 0.f);
    x[i] = gg * pp + (1.f - gg) * x[i];
  }
}

// ---------------------------------------------------------------------------
// persistent BiLSTM scan kernel, v5: unit-major gates + single-word poll.
//
// v4 post-mortem: every wave polling all 356 words (6/lane, whole-batch
// retry) octupled agent-scope poll traffic and induced contention
// near-livelock (dispatch variance 25ms..295ms). v5 keeps v4's unit-major
// compute (all 4 gate rows of a unit butterfly-reduced inside one wave ->
// publish right after the reduce, no barrier on the publish path) but
// restores v2's proven poll: each thread tid<356 spins on exactly ONE
// word and deposits it into a parity-double-buffered LDS h. The double
// buffer makes ONE __syncthreads per step sufficient (poll writes slot
// (t+1)&1; dots read slot t&1; the end-of-step barrier separates them).
// Waves owning zero units must NOT exit (their threads poll); they skip
// dots/publish only. Numerics identical to v2/v3/v4.
// ---------------------------------------------------------------------------
#define NWG 16
#define SLICE 23   // 16*23 = 368 >= 356
#define NU 3       // units per wave (8 waves * 3 = 24 >= 23)

__global__ __launch_bounds__(512, 1) void lstm_scan_kernel(
    const float* __restrict__ xw, const float* __restrict__ whh,
    const float* __restrict__ h0, float* __restrict__ out,
    int row0, int N, unsigned long long* exbuf,
    const float* __restrict__ h0b, int row0b, int Nb,
    unsigned long long* exbufb)
{
  int bid = blockIdx.x;
  if (bid >= 2 * NWG) {          // optional second problem
    bid -= 2 * NWG;
    h0 = h0b; row0 = row0b; N = Nb; exbuf = exbufb;
    if (N <= 0) return;
  }
  const int tid  = threadIdx.x;
  const int dir  = bid & 1;
  const int wg   = bid >> 1;
  const int lane = tid & 63;
  const int wv   = tid >> 6;          // 0..7
  const int j0   = wg * SLICE;
  const int base_u = wv * NU;
  const float* whh_d = whh + (size_t)dir * 1424 * 356;
  const float* h0_d  = h0 + dir * 356;
  const int xcol0 = dir * 1424;
  const int ocol0 = dir * 356;
  unsigned long long* exd = exbuf + (size_t)dir * 712;   // [parity][356]

  __shared__ float h_lds[2 * 384];    // [parity][384], 356..383 zero pad

  // number of valid units owned by this wave (prefix-valid)
  int nu = 0;
#pragma unroll
  for (int u = 0; u < NU; ++u) {
    int uu = base_u + u;
    if (uu < SLICE && (j0 + uu) < 356) nu = u + 1;
  }
  // NOTE: no early return for nu==0 — those threads still poll + barrier.

  // Whh rows -> registers. Row q = u*4 + g covers gate g of unit j0+base_u+u.
  float wreg[12][6];
#pragma unroll
  for (int q = 0; q < 12; ++q) {
    int u = q >> 2, g = q & 3;
    bool v = (u < nu);
    int j = j0 + base_u + (v ? u : 0);
    const float* wrow = whh_d + (size_t)(g * 356 + j) * 356;
#pragma unroll
    for (int ii = 0; ii < 6; ++ii) {
      int k = lane + ii * 64;
      wreg[q][ii] = (v && k < 356) ? wrow[k] : 0.f;
    }
  }

  // init LDS h: slot 0 = h0 (pad 0), slot 1 = 0
  for (int k = tid; k < 768; k += 512) {
    int sl = (k >= 384) ? 1 : 0;
    int idx = k - sl * 384;
    h_lds[k] = (sl == 0 && idx < 356) ? h0_d[idx] : 0.f;
  }

  // lane u (u < nu) owns unit ju: cell state + its 4 xw gate streams
  const bool uown = (lane < nu);
  const int  ju   = j0 + base_u + (uown ? lane : 0);
  float c_reg = uown ? h0_d[ju] : 0.f;
  const size_t xoff = (size_t)(xcol0 + ju);

  float xw_cur[4];
  {
    int row = dir ? (N - 1) : 0;
    size_t rb = (size_t)(row0 + row) * 2848 + xoff;
#pragma unroll
    for (int g = 0; g < 4; ++g) xw_cur[g] = uown ? xw[rb + g * 356] : 0.f;
  }
  __syncthreads();

  for (int t = 0; t < N; ++t) {
    int row = dir ? (N - 1 - t) : t;
    size_t grow = (size_t)(row0 + row);

    // load h(t) from LDS slot t&1 into registers
    const float* hbuf = h_lds + (size_t)(t & 1) * 384;
    float hreg[6];
#pragma unroll
    for (int ii = 0; ii < 6; ++ii) hreg[ii] = hbuf[lane + ii * 64];

    // issue next-step xw prefetch (covered by this step's compute+poll)
    float xw_nx[4];
#pragma unroll
    for (int g = 0; g < 4; ++g) xw_nx[g] = 0.f;
    if (t + 1 < N) {
      int rown = dir ? (N - 2 - t) : (t + 1);
      size_t rb = (size_t)(row0 + rown) * 2848 + xoff;
#pragma unroll
      for (int g = 0; g < 4; ++g) xw_nx[g] = uown ? xw[rb + g * 356] : 0.f;
    }

    // dots: s[q] = Whh_row_q . h   (12 independent rows, interleaved butterfly)
    float s[12];
#pragma unroll
    for (int q = 0; q < 12; ++q) {
      float v = wreg[q][0] * hreg[0];
#pragma unroll
      for (int ii = 1; ii < 6; ++ii) v += wreg[q][ii] * hreg[ii];
      s[q] = v;
    }
#pragma unroll
    for (int off = 32; off > 0; off >>= 1) {
#pragma unroll
      for (int q = 0; q < 12; ++q) s[q] += __shfl_xor(s[q], off);
    }

    // gate math + publish: lane u uses s[4u .. 4u+3] and its own xw gates
    float zi, zf, zg, zo;
    if (lane == 1)      { zi = s[4]; zf = s[5]; zg = s[6];  zo = s[7];  }
    else if (lane == 2) { zi = s[8]; zf = s[9]; zg = s[10]; zo = s[11]; }
    else                { zi = s[0]; zf = s[1]; zg = s[2];  zo = s[3];  }

    if (uown) {
      float c = sigm(zf + xw_cur[1]) * c_reg + sigm(zi + xw_cur[0]) * tanhf(zg + xw_cur[2]);
      float h = sigm(zo + xw_cur[3]) * tanhf(c);
      c_reg = c;
      unsigned long long pk =
          ((unsigned long long)(unsigned)(t + 1) << 32) |
          (unsigned long long)__float_as_uint(h);
      __hip_atomic_store(&exd[(size_t)(t & 1) * 356 + ju], pk,
                         __ATOMIC_RELAXED, __HIP_MEMORY_SCOPE_AGENT);
      out[grow * 712 + ocol0 + ju] = h;
    }

    // poll: each thread owns ONE word; deposit into slot (t+1)&1
    if (t + 1 < N) {
      if (tid < 356) {
        unsigned long long* p = &exd[(size_t)(t & 1) * 356 + tid];
        unsigned ep = (unsigned)(t + 1);
        unsigned long long v;
        do {
          v = __hip_atomic_load(p, __ATOMIC_RELAXED, __HIP_MEMORY_SCOPE_AGENT);
        } while ((unsigned)(v >> 32) != ep);
        h_lds[(size_t)((t + 1) & 1) * 384 + tid] = __uint_as_float((unsigned)v);
      }
    }
    __syncthreads();

#pragma unroll
    for (int g = 0; g < 4; ++g) xw_cur[g] = xw_nx[g];
  }
}

// ---------------------------------------------------------------------------
// attention: s2[j] = Q[j] . w_q
// ---------------------------------------------------------------------------
__global__ __launch_bounds__(64) void qdot_kernel(
    const float* __restrict__ Q, const float* __restrict__ sim_w, float* __restrict__ s2)
{
  int j = blockIdx.x;
  int lane = threadIdx.x;
  const float* q  = Q + (size_t)j * 712;
  const float* wq = sim_w + 712;
  float s = 0.f;
  for (int k = lane; k < 712; k += 64) s += q[k] * wq[k];
  s = waveSum(s);
  if (lane == 0) s2[j] = s;
}

// ---------------------------------------------------------------------------
// per-context-row attention + qac[0,2136)
// ---------------------------------------------------------------------------
__global__ __launch_bounds__(256) void attn_row_kernel(
    const float* __restrict__ CQ, const float* __restrict__ sim_w,
    const float* __restrict__ s2, float* __restrict__ rowm, float* __restrict__ qac)
{
  int i = blockIdx.x;   // 0..4095
  int tid = threadIdx.x;
  const float* Q = CQ + (size_t)4096 * 712;
  __shared__ float crow[712], cw[712], prow[128], red[256];
  const float* ci = CQ + (size_t)i * 712;

  float s1p = 0.f;
  for (int k = tid; k < 712; k += 256) {
    float v = ci[k];
    crow[k] = v;
    cw[k] = v * sim_w[1424 + k];
    s1p += v * sim_w[k];
  }
  red[tid] = s1p;
  __syncthreads();
  for (int s = 128; s > 0; s >>= 1) { if (tid < s) red[tid] += red[tid + s]; __syncthreads(); }
  float s1 = red[0];

  int lane = tid & 63, wv = tid >> 6;
  for (int j = wv; j < 128; j += 4) {
    const float* qj = Q + (size_t)j * 712;
    float s = 0.f;
    for (int k = lane; k < 712; k += 64) s += cw[k] * qj[k];
    s = waveSum(s);
    if (lane == 0) prow[j] = s1 + s2[j] + s;
  }
  __syncthreads();

  float v = (tid < 128) ? prow[tid] : -1e30f;
  red[tid] = v;
  __syncthreads();
  for (int s = 128; s > 0; s >>= 1) { if (tid < s) red[tid] = fmaxf(red[tid], red[tid + s]); __syncthreads(); }
  float m = red[0];
  __syncthreads();
  float e = (tid < 128) ? __expf(prow[tid] - m) : 0.f;
  red[tid] = e;
  __syncthreads();
  for (int s = 128; s > 0; s >>= 1) { if (tid < s) red[tid] += red[tid + s]; __syncthreads(); }
  float denom = red[0];
  if (tid < 128) prow[tid] = e / denom;
  if (tid == 0) rowm[i] = m;
  __syncthreads();

  size_t qb = (size_t)i * 2848;
  for (int k = tid; k < 712; k += 256) {
    float acc = 0.f;
    for (int j = 0; j < 128; ++j) acc += prow[j] * Q[(size_t)j * 712 + k];
    float cv = crow[k];
    qac[qb + k]        = cv;
    qac[qb + 712 + k]  = acc;
    qac[qb + 1424 + k] = cv * acc;
  }
}

// ---------------------------------------------------------------------------
// softmax over a length-4096 vector (single block)
// ---------------------------------------------------------------------------
__global__ __launch_bounds__(256) void softmax_4096(const float* __restrict__ in,
                                                    float* __restrict__ out)
{
  __shared__ float red[256];
  int tid = threadIdx.x;
  float m = -1e30f;
  for (int i = tid; i < 4096; i += 256) m = fmaxf(m, in[i]);
  red[tid] = m;
  __syncthreads();
  for (int s = 128; s > 0; s >>= 1) { if (tid < s) red[tid] = fmaxf(red[tid], red[tid + s]); __syncthreads(); }
  m = red[0];
  __syncthreads();
  float sum = 0.f;
  for (int i = tid; i < 4096; i += 256) sum += __expf(in[i] - m);
  red[tid] = sum;
  __syncthreads();
  for (int s = 128; s > 0; s >>= 1) { if (tid < s) red[tid] += red[tid + s]; __syncthreads(); }
  float denom = red[0];
  for (int i = tid; i < 4096; i += 256) out[i] = __expf(in[i] - m) / denom;
}

// ---------------------------------------------------------------------------
// q2c[k] = sum_i a[i]*C[i,k]
// ---------------------------------------------------------------------------
__global__ __launch_bounds__(256) void q2c_kernel(
    const float* __restrict__ CQ, const float* __restrict__ rowa, float* __restrict__ q2c)
{
  int k = blockIdx.x * 256 + threadIdx.x;
  if (k < 712) {
    float acc = 0.f;
    for (int i = 0; i < 4096; ++i) acc += rowa[i] * CQ[(size_t)i * 712 + k];
    q2c[k] = acc;
  }
}

__global__ __launch_bounds__(256) void qac_finish_kernel(
    const float* __restrict__ CQ, const float* __restrict__ q2c, float* __restrict__ qac)
{
  int i = blockIdx.x;
  int tid = threadIdx.x;
  for (int k = tid; k < 712; k += 256)
    qac[(size_t)i * 2848 + 2136 + k] = CQ[(size_t)i * 712 + k] * q2c[k];
}

__global__ __launch_bounds__(256) void logits_kernel(
    const float* __restrict__ qac, const float* __restrict__ Mx,
    const float* __restrict__ w, float* __restrict__ logits)
{
  int i = blockIdx.x, tid = threadIdx.x;
  __shared__ float red[256];
  float s = 0.f;
  const float* qr = qac + (size_t)i * 2848;
  for (int k = tid; k < 2848; k += 256) s += qr[k] * w[k];
  const float* mr = Mx + (size_t)i * 712;
  for (int k = tid; k < 712; k += 256) s += mr[k] * w[2848 + k];
  red[tid] = s;
  __syncthreads();
  for (int st = 128; st > 0; st >>= 1) { if (tid < st) red[tid] += red[tid + st]; __syncthreads(); }
  if (tid == 0) logits[i] = red[0];
}

// ---------------------------------------------------------------------------
// host side
// ---------------------------------------------------------------------------
extern "C" void kernel_launch(void* const* d_in, const int* in_sizes, int n_in,
                              void* d_out, int out_size, void* d_ws, size_t ws_size,
                              hipStream_t stream)
{
  const int*   chars_ctx = (const int*)d_in[0];
  const int*   chars_qry = (const int*)d_in[1];
  const float* elmo_ctx  = (const float*)d_in[2];
  const float* elmo_qry  = (const float*)d_in[3];
  const float* char_emb  = (const float*)d_in[4];
  const float* conv_w    = (const float*)d_in[5];
  const float* conv_b    = (const float*)d_in[6];
  const float* hw_plain_w = (const float*)d_in[7];
  const float* hw_plain_b = (const float*)d_in[8];
  const float* hw_gate_w  = (const float*)d_in[9];
  const float* hw_gate_b  = (const float*)d_in[10];
  const float* ctx_Wih   = (const float*)d_in[11];
  const float* ctx_Whh   = (const float*)d_in[12];
  const float* ctx_b     = (const float*)d_in[13];
  const float* sim_w     = (const float*)d_in[14];
  const float* mod1_Wih  = (const float*)d_in[15];
  const float* mod1_Whh  = (const float*)d_in[16];
  const float* mod1_b    = (const float*)d_in[17];
  const float* mod2_Wih  = (const float*)d_in[18];
  const float* mod2_Whh  = (const float*)d_in[19];
  const float* mod2_b    = (const float*)d_in[20];
  const float* pos_Wih   = (const float*)d_in[21];
  const float* pos_Whh   = (const float*)d_in[22];
  const float* pos_b     = (const float*)d_in[23];
  const float* pos1_w    = (const float*)d_in[24];
  const float* pos2_w    = (const float*)d_in[25];
  const float* h0_ctx_c  = (const float*)d_in[26];
  const float* h0_ctx_q  = (const float*)d_in[27];
  const float* h0_mod    = (const float*)d_in[28];
  const float* h0_pos    = (const float*)d_in[29];
  float* outp = (float*)d_out;

  float* ws = (float*)d_ws;
  size_t off = 0;
  auto alloc = [&](size_t n) { float* p = ws + off; off += n; return p; };
  float* x_all  = alloc(4224ull * 356);
  float* gbuf   = alloc(4224ull * 356);
  float* pbuf   = alloc(4224ull * 356);
  float* xw_all = alloc(4224ull * 2848);
  float* CQ     = alloc(4224ull * 712);
  float* M1     = alloc(4096ull * 712);
  float* Mm     = alloc(4096ull * 712);
  float* M2     = alloc(4096ull * 712);
  float* qac    = alloc(4096ull * 2848);
  float* s2v    = alloc(128);
  float* rowm   = alloc(4096);
  float* rowa   = alloc(4096);
  float* q2cv   = alloc(1024);
  float* logits = alloc(8192);
  off = (off + 1) & ~(size_t)1;                    // 8B align
  unsigned long long* exbuf = (unsigned long long*)(ws + off);
  // 5 scans x [2 dirs][2 parity][356] u64 — poisoned 0xAA by the harness;
  // 0xAAAAAAAA never equals any epoch t+1 <= 4096, so no memset needed.
  off += 5ull * 1424 * 2;

  auto cdiv = [](int a, int b) { return (a + b - 1) / b; };

  // 1) char CNN + elmo concat
  cnn_embed_kernel<<<4224, 128, 0, stream>>>(chars_ctx, chars_qry, elmo_ctx, elmo_qry,
                                             char_emb, conv_w, conv_b, x_all);

  // 2) highway x2
  for (int l = 0; l < 2; ++l) {
    gemm_abt<<<dim3(cdiv(356, BNT), cdiv(4224, BMT)), 256, 0, stream>>>(
        x_all, hw_gate_w + (size_t)l * 356 * 356, hw_gate_b + l * 356, gbuf, 4224, 356, 356);
    gemm_abt<<<dim3(cdiv(356, BNT), cdiv(4224, BMT)), 256, 0, stream>>>(
        x_all, hw_plain_w + (size_t)l * 356 * 356, hw_plain_b + l * 356, pbuf, 4224, 356, 356);
    highway_combine<<<cdiv(4224 * 356, 256), 256, 0, stream>>>(x_all, gbuf, pbuf, 4224 * 356);
  }

  // 3) ctx BiLSTM — ctx (4096 steps) and qry (128 steps) ride one dispatch
  gemm_abt<<<dim3(cdiv(2848, BNT), cdiv(4224, BMT)), 256, 0, stream>>>(
      x_all, ctx_Wih, ctx_b, xw_all, 4224, 2848, 356);
  lstm_scan_kernel<<<4 * NWG, 512, 0, stream>>>(xw_all, ctx_Whh, h0_ctx_c, CQ, 0, 4096,
                                                exbuf + 0ull * 1424,
                                                h0_ctx_q, 4096, 128,
                                                exbuf + 1ull * 1424);

  // 4) attention
  qdot_kernel<<<128, 64, 0, stream>>>(CQ + 4096ull * 712, sim_w, s2v);
  attn_row_kernel<<<4096, 256, 0, stream>>>(CQ, sim_w, s2v, rowm, qac);
  softmax_4096<<<1, 256, 0, stream>>>(rowm, rowa);
  q2c_kernel<<<cdiv(712, 256), 256, 0, stream>>>(CQ, rowa, q2cv);
  qac_finish_kernel<<<4096, 256, 0, stream>>>(CQ, q2cv, qac);

  // 5) mod1 BiLSTM (input 2848)
  gemm_abt<<<dim3(cdiv(2848, BNT), cdiv(4096, BMT)), 256, 0, stream>>>(
      qac, mod1_Wih, mod1_b, xw_all, 4096, 2848, 2848);
  lstm_scan_kernel<<<2 * NWG, 512, 0, stream>>>(xw_all, mod1_Whh, h0_mod, M1, 0, 4096,
                                                exbuf + 2ull * 1424,
                                                nullptr, 0, 0, nullptr);

  // 6) mod2 BiLSTM (input 712)
  gemm_abt<<<dim3(cdiv(2848, BNT), cdiv(4096, BMT)), 256, 0, stream>>>(
      M1, mod2_Wih, mod2_b, xw_all, 4096, 2848, 712);
  lstm_scan_kernel<<<2 * NWG, 512, 0, stream>>>(xw_all, mod2_Whh, h0_mod + 712, Mm, 0, 4096,
                                                exbuf + 3ull * 1424,
                                                nullptr, 0, 0, nullptr);

  // 7) pos1
  logits_kernel<<<4096, 256, 0, stream>>>(qac, Mm, pos1_w, logits);
  softmax_4096<<<1, 256, 0, stream>>>(logits, outp);

  // 8) pos BiLSTM then pos2
  gemm_abt<<<dim3(cdiv(2848, BNT), cdiv(4096, BMT)), 256, 0, stream>>>(
      Mm, pos_Wih, pos_b, xw_all, 4096, 2848, 712);
  lstm_scan_kernel<<<2 * NWG, 512, 0, stream>>>(xw_all, pos_Whh, h0_pos, M2, 0, 4096,
                                                exbuf + 4ull * 1424,
                                                nullptr, 0, 0, nullptr);
  logits_kernel<<<4096, 256, 0, stream>>>(qac, M2, pos2_w, logits + 4096);
  softmax_4096<<<1, 256, 0, stream>>>(logits + 4096, outp + 4096);

  (void)in_sizes; (void)n_in; (void)out_size; (void)ws_size;
}

// Round 4
// 60070.056 us; speedup vs baseline: 1.8817x; 1.4010x over previous
//
#include <hip/hip_runtime.h>
#include <math.h>

// ---------------------------------------------------------------------------
// helpers
// ---------------------------------------------------------------------------
__device__ __forceinline__ float sigm(float x) { return 1.0f / (1.0f + __expf(-x)); }

__device__ __forceinline__ float waveSum(float v) {
#pragma unroll
  for (int off = 32; off > 0; off >>= 1) v += __shfl_xor(v, off);
  return v;
}

// ---------------------------------------------------------------------------
// char CNN + elmo concat  -> x_all (4224 x 356)
// ---------------------------------------------------------------------------
__global__ __launch_bounds__(128) void cnn_embed_kernel(
    const int* __restrict__ chars_ctx, const int* __restrict__ chars_qry,
    const float* __restrict__ elmo_ctx, const float* __restrict__ elmo_qry,
    const float* __restrict__ char_emb, const float* __restrict__ conv_w,
    const float* __restrict__ conv_b, float* __restrict__ x_all)
{
  int n = blockIdx.x;
  const int*   chars = (n < 4096) ? (chars_ctx + n * 16) : (chars_qry + (n - 4096) * 16);
  const float* elmo  = (n < 4096) ? (elmo_ctx + (size_t)n * 256)
                                  : (elmo_qry + (size_t)(n - 4096) * 256);
  __shared__ float xl[1600];   // [emb_dim=100][pos=16]
  __shared__ int   cidx[16];
  int tid = threadIdx.x;
  if (tid < 16) cidx[tid] = chars[tid];
  __syncthreads();
  for (int e = tid; e < 1600; e += 128) {
    int i = e >> 4, p = e & 15;
    xl[e] = char_emb[cidx[p] * 100 + i];
  }
  __syncthreads();
  if (tid < 100) {
    int o = tid;
    float acc[16];
#pragma unroll
    for (int p = 0; p < 16; ++p) acc[p] = 0.f;
    const float* wo = conv_w + o * 500;
    for (int i = 0; i < 100; ++i) {
      const float* xi = xl + i * 16;
#pragma unroll
      for (int k = 0; k < 5; ++k) {
        float w = wo[i * 5 + k];
#pragma unroll
        for (int p = 0; p < 16; ++p) {
          int src = p + k - 2;
          if (src >= 0 && src < 16) acc[p] += w * xi[src];
        }
      }
    }
    float m = acc[0];
#pragma unroll
    for (int p = 1; p < 16; ++p) m = fmaxf(m, acc[p]);
    x_all[(size_t)n * 356 + o] = m + conv_b[o];
  }
  for (int j = tid; j < 256; j += 128)
    x_all[(size_t)n * 356 + 100 + j] = elmo[j];
}

// ---------------------------------------------------------------------------
// fp32 GEMM:  C[M,N] = A[M,K] @ B[N,K]^T + bias[N]
// v6: 128x128x16 tile, 256 threads, 8x8 acc/thread, float4 global loads.
// All K values used here (356, 712, 2136, 2848) are multiples of 4 and all
// row strides are 16B-aligned, so the vector path is aligned; the rare
// partial k-tile (K%16 != 0) falls back to checked scalar loads.
// ---------------------------------------------------------------------------
#define GBM 128
#define GBN 128
#define GBK 16

__global__ __launch_bounds__(256) void gemm_abt(
    const float* __restrict__ A, const float* __restrict__ B,
    const float* __restrict__ bias, float* __restrict__ C,
    int M, int N, int K)
{
  __shared__ float As[GBK][GBM + 4];
  __shared__ float Bs[GBK][GBN + 4];
  int tid = threadIdx.x;
  int bm = blockIdx.y * GBM, bn = blockIdx.x * GBN;
  int tx = tid & 15, ty = tid >> 4;       // 16 x 16 thread grid
  float acc[8][8];
#pragma unroll
  for (int i = 0; i < 8; ++i)
#pragma unroll
    for (int j = 0; j < 8; ++j) acc[i][j] = 0.f;

  for (int k0 = 0; k0 < K; k0 += GBK) {
    bool fullk = (k0 + GBK <= K);
    // A tile: 128 rows x 16 k = 512 float4 slots; 2 per thread
#pragma unroll
    for (int l = 0; l < 2; ++l) {
      int slot = tid * 2 + l;            // 0..511
      int r = slot >> 2, kq = slot & 3;  // row in tile, k-quad
      int gm = bm + r, gk = k0 + kq * 4;
      float vx = 0.f, vy = 0.f, vz = 0.f, vw = 0.f;
      if (gm < M) {
        if (fullk) {
          float4 v = *reinterpret_cast<const float4*>(&A[(size_t)gm * K + gk]);
          vx = v.x; vy = v.y; vz = v.z; vw = v.w;
        } else {
          const float* ar = A + (size_t)gm * K;
          if (gk + 0 < K) vx = ar[gk + 0];
          if (gk + 1 < K) vy = ar[gk + 1];
          if (gk + 2 < K) vz = ar[gk + 2];
          if (gk + 3 < K) vw = ar[gk + 3];
        }
      }
      As[kq * 4 + 0][r] = vx;
      As[kq * 4 + 1][r] = vy;
      As[kq * 4 + 2][r] = vz;
      As[kq * 4 + 3][r] = vw;
    }
    // B tile (same layout, N rows)
#pragma unroll
    for (int l = 0; l < 2; ++l) {
      int slot = tid * 2 + l;
      int r = slot >> 2, kq = slot & 3;
      int gn = bn + r, gk = k0 + kq * 4;
      float vx = 0.f, vy = 0.f, vz = 0.f, vw = 0.f;
      if (gn < N) {
        if (fullk) {
          float4 v = *reinterpret_cast<const float4*>(&B[(size_t)gn * K + gk]);
          vx = v.x; vy = v.y; vz = v.z; vw = v.w;
        } else {
          const float* br = B + (size_t)gn * K;
          if (gk + 0 < K) vx = br[gk + 0];
          if (gk + 1 < K) vy = br[gk + 1];
          if (gk + 2 < K) vz = br[gk + 2];
          if (gk + 3 < K) vw = br[gk + 3];
        }
      }
      Bs[kq * 4 + 0][r] = vx;
      Bs[kq * 4 + 1][r] = vy;
      Bs[kq * 4 + 2][r] = vz;
      Bs[kq * 4 + 3][r] = vw;
    }
    __syncthreads();
#pragma unroll
    for (int kk = 0; kk < GBK; ++kk) {
      float a[8], b[8];
#pragma unroll
      for (int i = 0; i < 8; ++i) a[i] = As[kk][ty * 8 + i];
#pragma unroll
      for (int j = 0; j < 8; ++j) b[j] = Bs[kk][tx * 8 + j];
#pragma unroll
      for (int i = 0; i < 8; ++i)
#pragma unroll
        for (int j = 0; j < 8; ++j) acc[i][j] += a[i] * b[j];
    }
    __syncthreads();
  }

  // bias per output column (registers)
  float bv[8];
#pragma unroll
  for (int j = 0; j < 8; ++j) {
    int gn = bn + tx * 8 + j;
    bv[j] = (bias && gn < N) ? bias[gn] : 0.f;
  }
#pragma unroll
  for (int i = 0; i < 8; ++i) {
    int gm = bm + ty * 8 + i;
    if (gm >= M) continue;
    float* crow = C + (size_t)gm * N;
    int gn0 = bn + tx * 8;
    if (gn0 + 8 <= N) {
      float4 o0, o1;
      o0.x = acc[i][0] + bv[0]; o0.y = acc[i][1] + bv[1];
      o0.z = acc[i][2] + bv[2]; o0.w = acc[i][3] + bv[3];
      o1.x = acc[i][4] + bv[4]; o1.y = acc[i][5] + bv[5];
      o1.z = acc[i][6] + bv[6]; o1.w = acc[i][7] + bv[7];
      *reinterpret_cast<float4*>(&crow[gn0])     = o0;
      *reinterpret_cast<float4*>(&crow[gn0 + 4]) = o1;
    } else {
#pragma unroll
      for (int j = 0; j < 8; ++j) {
        int gn = gn0 + j;
        if (gn < N) crow[gn] = acc[i][j] + bv[j];
      }
    }
  }
}

// ---------------------------------------------------------------------------
// highway combine
// ---------------------------------------------------------------------------
__global__ void highway_combine(float* __restrict__ x, const float* __restrict__ g,
                                const float* __restrict__ p, int total)
{
  int i = blockIdx.x * blockDim.x + threadIdx.x;
  if (i < total) {
    float gg = sigm(g[i]);
    float pp = fmaxf(p[i], 0.f);
    x[i] = gg * pp + (1.f - gg) * x[i];
  }
}

// ---------------------------------------------------------------------------
// persistent BiLSTM scan kernel, v6: v2's proven exchange topology
// (23 publishers / 356 single-word pollers / LDS h), with stage A removed:
//   - lane0 of wave wv WRITES its 12 Whh-dot results into z_lds (no +=,
//     no xw pre-init, no stage-A barrier),
//   - the 23 gate-owner threads (tid<23, wave 0) hold their unit's 4 xw
//     values in registers (coalesced 4x92B loads, prefetched one step
//     ahead) and add them at gate time (float add is commutative ->
//     bit-identical numerics to v2).
// 2 barriers/step instead of v2's 3. Publish happens right after barrier1.
// Lap-safety invariant unchanged: every WG both publishes and polls, so a
// publisher reaching step t+2 implies all WGs completed their step-t poll.
// ---------------------------------------------------------------------------
#define NWG 16
#define SLICE 23   // 16*23 = 368 >= 356

__global__ __launch_bounds__(512, 1) void lstm_scan_kernel(
    const float* __restrict__ xw, const float* __restrict__ whh,
    const float* __restrict__ h0, float* __restrict__ out,
    int row0, int N, unsigned long long* exbuf,
    const float* __restrict__ h0b, int row0b, int Nb,
    unsigned long long* exbufb)
{
  int bid = blockIdx.x;
  if (bid >= 2 * NWG) {          // optional second problem (qry scan)
    bid -= 2 * NWG;
    h0 = h0b; row0 = row0b; N = Nb; exbuf = exbufb;
    if (N <= 0) return;
  }
  const int tid  = threadIdx.x;
  const int dir  = bid & 1;
  const int wg   = bid >> 1;
  const int lane = tid & 63;
  const int wv   = tid >> 6;          // 0..7
  const int j0   = wg * SLICE;
  const float* whh_d = whh + (size_t)dir * 1424 * 356;
  const float* h0_d  = h0 + dir * 356;
  const int xcol0 = dir * 1424;
  const int ocol0 = dir * 356;
  unsigned long long* exd = exbuf + (size_t)dir * 712;   // [parity][356]

  __shared__ float h_lds[384];
  __shared__ float z_lds[4 * SLICE];   // [gate][jj] = Whh-dot only

  // Whh slice -> registers: wave wv, q=0..11 -> rr = wv*12+q
  float wreg[12][6];
#pragma unroll
  for (int q = 0; q < 12; ++q) {
    int rr = wv * 12 + q;
    bool rv = (rr < 4 * SLICE);
    int gate = rv ? (rr / SLICE) : 0, jj = rv ? (rr % SLICE) : 0;
    int j = j0 + jj;
    bool v = rv && (j < 356);
    int row_g = gate * 356 + j;
#pragma unroll
    for (int ii = 0; ii < 6; ++ii) {
      int k = lane + ii * 64;
      wreg[q][ii] = (v && k < 356) ? whh_d[(size_t)row_g * 356 + k] : 0.f;
    }
  }

  // init h (pad zeroed)
  for (int k = tid; k < 384; k += 512) h_lds[k] = (k < 356) ? h0_d[k] : 0.f;

  // gate-owner duty: tid<23, unit jg = j0+tid
  const bool guown = (tid < SLICE) && (j0 + tid) < 356;
  const int  jg    = j0 + (guown ? tid : 0);
  float c_reg = guown ? h0_d[jg] : 0.f;

  // xw prefetch for t=0: 4 coalesced 92B runs (one per gate)
  float xw_cur[4];
  {
    int row = dir ? (N - 1) : 0;
    size_t rb = (size_t)(row0 + row) * 2848;
#pragma unroll
    for (int g = 0; g < 4; ++g)
      xw_cur[g] = guown ? xw[rb + (size_t)(xcol0 + g * 356 + jg)] : 0.f;
  }
  __syncthreads();

  for (int t = 0; t < N; ++t) {
    int row = dir ? (N - 1 - t) : t;
    size_t grow = (size_t)(row0 + row);

    // issue next-step xw prefetch first (hidden under dots + barrier)
    float xw_nx[4];
#pragma unroll
    for (int g = 0; g < 4; ++g) xw_nx[g] = 0.f;
    if (t + 1 < N) {
      int rown = dir ? (N - 2 - t) : (t + 1);
      size_t rb = (size_t)(row0 + rown) * 2848;
#pragma unroll
      for (int g = 0; g < 4; ++g)
        xw_nx[g] = guown ? xw[rb + (size_t)(xcol0 + g * 356 + jg)] : 0.f;
    }

    // dots: s[q] = Whh_row_q . h  (12 rows/wave, interleaved butterfly)
    float s[12];
#pragma unroll
    for (int q = 0; q < 12; ++q) {
      float v = wreg[q][0] * h_lds[lane];
#pragma unroll
      for (int ii = 1; ii < 6; ++ii) v += wreg[q][ii] * h_lds[lane + ii * 64];
      s[q] = v;
    }
#pragma unroll
    for (int off = 32; off > 0; off >>= 1) {
#pragma unroll
      for (int q = 0; q < 12; ++q) s[q] += __shfl_xor(s[q], off);
    }
    if (lane == 0) {
#pragma unroll
      for (int q = 0; q < 12; ++q) {
        int rr = wv * 12 + q;
        if (rr < 4 * SLICE) z_lds[rr] = s[q];
      }
    }
    __syncthreads();   // barrier1: z ready; h_lds now dead

    // gates + publish (tid<23) and poll (tid<356) — concurrent duties
    if (guown) {
      float zi = z_lds[tid]             + xw_cur[0];
      float zf = z_lds[SLICE + tid]     + xw_cur[1];
      float zg = z_lds[2 * SLICE + tid] + xw_cur[2];
      float zo = z_lds[3 * SLICE + tid] + xw_cur[3];
      float c = sigm(zf) * c_reg + sigm(zi) * tanhf(zg);
      float h = sigm(zo) * tanhf(c);
      c_reg = c;
      unsigned long long pk =
          ((unsigned long long)(unsigned)(t + 1) << 32) |
          (unsigned long long)__float_as_uint(h);
      __hip_atomic_store(&exd[(size_t)(t & 1) * 356 + jg], pk,
                         __ATOMIC_RELAXED, __HIP_MEMORY_SCOPE_AGENT);
      out[grow * 712 + ocol0 + jg] = h;
    }
    if (t + 1 < N && tid < 356) {
      unsigned long long* p = &exd[(size_t)(t & 1) * 356 + tid];
      unsigned ep = (unsigned)(t + 1);
      unsigned long long v;
      do {
        v = __hip_atomic_load(p, __ATOMIC_RELAXED, __HIP_MEMORY_SCOPE_AGENT);
      } while ((unsigned)(v >> 32) != ep);
      h_lds[tid] = __uint_as_float((unsigned)v);
    }
    __syncthreads();   // barrier2: h(t+1) ready

#pragma unroll
    for (int g = 0; g < 4; ++g) xw_cur[g] = xw_nx[g];
  }
}

// ---------------------------------------------------------------------------
// attention: s2[j] = Q[j] . w_q
// ---------------------------------------------------------------------------
__global__ __launch_bounds__(64) void qdot_kernel(
    const float* __restrict__ Q, const float* __restrict__ sim_w, float* __restrict__ s2)
{
  int j = blockIdx.x;
  int lane = threadIdx.x;
  const float* q  = Q + (size_t)j * 712;
  const float* wq = sim_w + 712;
  float s = 0.f;
  for (int k = lane; k < 712; k += 64) s += q[k] * wq[k];
  s = waveSum(s);
  if (lane == 0) s2[j] = s;
}

// ---------------------------------------------------------------------------
// per-context-row attention + qac[0,2136)
// ---------------------------------------------------------------------------
__global__ __launch_bounds__(256) void attn_row_kernel(
    const float* __restrict__ CQ, const float* __restrict__ sim_w,
    const float* __restrict__ s2, float* __restrict__ rowm, float* __restrict__ qac)
{
  int i = blockIdx.x;   // 0..4095
  int tid = threadIdx.x;
  const float* Q = CQ + (size_t)4096 * 712;
  __shared__ float crow[712], cw[712], prow[128], red[256];
  const float* ci = CQ + (size_t)i * 712;

  float s1p = 0.f;
  for (int k = tid; k < 712; k += 256) {
    float v = ci[k];
    crow[k] = v;
    cw[k] = v * sim_w[1424 + k];
    s1p += v * sim_w[k];
  }
  red[tid] = s1p;
  __syncthreads();
  for (int s = 128; s > 0; s >>= 1) { if (tid < s) red[tid] += red[tid + s]; __syncthreads(); }
  float s1 = red[0];

  int lane = tid & 63, wv = tid >> 6;
  for (int j = wv; j < 128; j += 4) {
    const float* qj = Q + (size_t)j * 712;
    float s = 0.f;
    for (int k = lane; k < 712; k += 64) s += cw[k] * qj[k];
    s = waveSum(s);
    if (lane == 0) prow[j] = s1 + s2[j] + s;
  }
  __syncthreads();

  float v = (tid < 128) ? prow[tid] : -1e30f;
  red[tid] = v;
  __syncthreads();
  for (int s = 128; s > 0; s >>= 1) { if (tid < s) red[tid] = fmaxf(red[tid], red[tid + s]); __syncthreads(); }
  float m = red[0];
  __syncthreads();
  float e = (tid < 128) ? __expf(prow[tid] - m) : 0.f;
  red[tid] = e;
  __syncthreads();
  for (int s = 128; s > 0; s >>= 1) { if (tid < s) red[tid] += red[tid + s]; __syncthreads(); }
  float denom = red[0];
  if (tid < 128) prow[tid] = e / denom;
  if (tid == 0) rowm[i] = m;
  __syncthreads();

  size_t qb = (size_t)i * 2848;
  for (int k = tid; k < 712; k += 256) {
    float acc = 0.f;
    for (int j = 0; j < 128; ++j) acc += prow[j] * Q[(size_t)j * 712 + k];
    float cv = crow[k];
    qac[qb + k]        = cv;
    qac[qb + 712 + k]  = acc;
    qac[qb + 1424 + k] = cv * acc;
  }
}

// ---------------------------------------------------------------------------
// softmax over a length-4096 vector (single block)
// ---------------------------------------------------------------------------
__global__ __launch_bounds__(256) void softmax_4096(const float* __restrict__ in,
                                                    float* __restrict__ out)
{
  __shared__ float red[256];
  int tid = threadIdx.x;
  float m = -1e30f;
  for (int i = tid; i < 4096; i += 256) m = fmaxf(m, in[i]);
  red[tid] = m;
  __syncthreads();
  for (int s = 128; s > 0; s >>= 1) { if (tid < s) red[tid] = fmaxf(red[tid], red[tid + s]); __syncthreads(); }
  m = red[0];
  __syncthreads();
  float sum = 0.f;
  for (int i = tid; i < 4096; i += 256) sum += __expf(in[i] - m);
  red[tid] = sum;
  __syncthreads();
  for (int s = 128; s > 0; s >>= 1) { if (tid < s) red[tid] += red[tid + s]; __syncthreads(); }
  float denom = red[0];
  for (int i = tid; i < 4096; i += 256) out[i] = __expf(in[i] - m) / denom;
}

// ---------------------------------------------------------------------------
// q2c[k] = sum_i a[i]*C[i,k]
// ---------------------------------------------------------------------------
__global__ __launch_bounds__(256) void q2c_kernel(
    const float* __restrict__ CQ, const float* __restrict__ rowa, float* __restrict__ q2c)
{
  int k = blockIdx.x * 256 + threadIdx.x;
  if (k < 712) {
    float acc = 0.f;
    for (int i = 0; i < 4096; ++i) acc += rowa[i] * CQ[(size_t)i * 712 + k];
    q2c[k] = acc;
  }
}

__global__ __launch_bounds__(256) void qac_finish_kernel(
    const float* __restrict__ CQ, const float* __restrict__ q2c, float* __restrict__ qac)
{
  int i = blockIdx.x;
  int tid = threadIdx.x;
  for (int k = tid; k < 712; k += 256)
    qac[(size_t)i * 2848 + 2136 + k] = CQ[(size_t)i * 712 + k] * q2c[k];
}

__global__ __launch_bounds__(256) void logits_kernel(
    const float* __restrict__ qac, const float* __restrict__ Mx,
    const float* __restrict__ w, float* __restrict__ logits)
{
  int i = blockIdx.x, tid = threadIdx.x;
  __shared__ float red[256];
  float s = 0.f;
  const float* qr = qac + (size_t)i * 2848;
  for (int k = tid; k < 2848; k += 256) s += qr[k] * w[k];
  const float* mr = Mx + (size_t)i * 712;
  for (int k = tid; k < 712; k += 256) s += mr[k] * w[2848 + k];
  red[tid] = s;
  __syncthreads();
  for (int st = 128; st > 0; st >>= 1) { if (tid < st) red[tid] += red[tid + st]; __syncthreads(); }
  if (tid == 0) logits[i] = red[0];
}

// ---------------------------------------------------------------------------
// host side
// ---------------------------------------------------------------------------
extern "C" void kernel_launch(void* const* d_in, const int* in_sizes, int n_in,
                              void* d_out, int out_size, void* d_ws, size_t ws_size,
                              hipStream_t stream)
{
  const int*   chars_ctx = (const int*)d_in[0];
  const int*   chars_qry = (const int*)d_in[1];
  const float* elmo_ctx  = (const float*)d_in[2];
  const float* elmo_qry  = (const float*)d_in[3];
  const float* char_emb  = (const float*)d_in[4];
  const float* conv_w    = (const float*)d_in[5];
  const float* conv_b    = (const float*)d_in[6];
  const float* hw_plain_w = (const float*)d_in[7];
  const float* hw_plain_b = (const float*)d_in[8];
  const float* hw_gate_w  = (const float*)d_in[9];
  const float* hw_gate_b  = (const float*)d_in[10];
  const float* ctx_Wih   = (const float*)d_in[11];
  const float* ctx_Whh   = (const float*)d_in[12];
  const float* ctx_b     = (const float*)d_in[13];
  const float* sim_w     = (const float*)d_in[14];
  const float* mod1_Wih  = (const float*)d_in[15];
  const float* mod1_Whh  = (const float*)d_in[16];
  const float* mod1_b    = (const float*)d_in[17];
  const float* mod2_Wih  = (const float*)d_in[18];
  const float* mod2_Whh  = (const float*)d_in[19];
  const float* mod2_b    = (const float*)d_in[20];
  const float* pos_Wih   = (const float*)d_in[21];
  const float* pos_Whh   = (const float*)d_in[22];
  const float* pos_b     = (const float*)d_in[23];
  const float* pos1_w    = (const float*)d_in[24];
  const float* pos2_w    = (const float*)d_in[25];
  const float* h0_ctx_c  = (const float*)d_in[26];
  const float* h0_ctx_q  = (const float*)d_in[27];
  const float* h0_mod    = (const float*)d_in[28];
  const float* h0_pos    = (const float*)d_in[29];
  float* outp = (float*)d_out;

  float* ws = (float*)d_ws;
  size_t off = 0;
  auto alloc = [&](size_t n) { float* p = ws + off; off += n; return p; };
  float* x_all  = alloc(4224ull * 356);
  float* gbuf   = alloc(4224ull * 356);
  float* pbuf   = alloc(4224ull * 356);
  float* xw_all = alloc(4224ull * 2848);
  float* CQ     = alloc(4224ull * 712);
  float* M1     = alloc(4096ull * 712);
  float* Mm     = alloc(4096ull * 712);
  float* M2     = alloc(4096ull * 712);
  float* qac    = alloc(4096ull * 2848);
  float* s2v    = alloc(128);
  float* rowm   = alloc(4096);
  float* rowa   = alloc(4096);
  float* q2cv   = alloc(1024);
  float* logits = alloc(8192);
  off = (off + 1) & ~(size_t)1;                    // 8B align
  unsigned long long* exbuf = (unsigned long long*)(ws + off);
  // 5 scans x [2 dirs][2 parity][356] u64 — poisoned 0xAA by the harness;
  // 0xAAAAAAAA never equals any epoch t+1 <= 4096, so no memset needed.
  off += 5ull * 1424 * 2;

  auto cdiv = [](int a, int b) { return (a + b - 1) / b; };

  // 1) char CNN + elmo concat
  cnn_embed_kernel<<<4224, 128, 0, stream>>>(chars_ctx, chars_qry, elmo_ctx, elmo_qry,
                                             char_emb, conv_w, conv_b, x_all);

  // 2) highway x2
  for (int l = 0; l < 2; ++l) {
    gemm_abt<<<dim3(cdiv(356, GBN), cdiv(4224, GBM)), 256, 0, stream>>>(
        x_all, hw_gate_w + (size_t)l * 356 * 356, hw_gate_b + l * 356, gbuf, 4224, 356, 356);
    gemm_abt<<<dim3(cdiv(356, GBN), cdiv(4224, GBM)), 256, 0, stream>>>(
        x_all, hw_plain_w + (size_t)l * 356 * 356, hw_plain_b + l * 356, pbuf, 4224, 356, 356);
    highway_combine<<<cdiv(4224 * 356, 256), 256, 0, stream>>>(x_all, gbuf, pbuf, 4224 * 356);
  }

  // 3) ctx BiLSTM — ctx (4096 steps) and qry (128 steps) ride one dispatch
  gemm_abt<<<dim3(cdiv(2848, GBN), cdiv(4224, GBM)), 256, 0, stream>>>(
      x_all, ctx_Wih, ctx_b, xw_all, 4224, 2848, 356);
  lstm_scan_kernel<<<4 * NWG, 512, 0, stream>>>(xw_all, ctx_Whh, h0_ctx_c, CQ, 0, 4096,
                                                exbuf + 0ull * 1424,
                                                h0_ctx_q, 4096, 128,
                                                exbuf + 1ull * 1424);

  // 4) attention
  qdot_kernel<<<128, 64, 0, stream>>>(CQ + 4096ull * 712, sim_w, s2v);
  attn_row_kernel<<<4096, 256, 0, stream>>>(CQ, sim_w, s2v, rowm, qac);
  softmax_4096<<<1, 256, 0, stream>>>(rowm, rowa);
  q2c_kernel<<<cdiv(712, 256), 256, 0, stream>>>(CQ, rowa, q2cv);
  qac_finish_kernel<<<4096, 256, 0, stream>>>(CQ, q2cv, qac);

  // 5) mod1 BiLSTM (input 2848)
  gemm_abt<<<dim3(cdiv(2848, GBN), cdiv(4096, GBM)), 256, 0, stream>>>(
      qac, mod1_Wih, mod1_b, xw_all, 4096, 2848, 2848);
  lstm_scan_kernel<<<2 * NWG, 512, 0, stream>>>(xw_all, mod1_Whh, h0_mod, M1, 0, 4096,
                                                exbuf + 2ull * 1424,
                                                nullptr, 0, 0, nullptr);

  // 6) mod2 BiLSTM (input 712)
  gemm_abt<<<dim3(cdiv(2848, GBN), cdiv(4096, GBM)), 256, 0, stream>>>(
      M1, mod2_Wih, mod2_b, xw_all, 4096, 2848, 712);
  lstm_scan_kernel<<<2 * NWG, 512, 0, stream>>>(xw_all, mod2_Whh, h0_mod + 712, Mm, 0, 4096,
                                                exbuf + 3ull * 1424,
                                                nullptr, 0, 0, nullptr);

  // 7) pos1
  logits_kernel<<<4096, 256, 0, stream>>>(qac, Mm, pos1_w, logits);
  softmax_4096<<<1, 256, 0, stream>>>(logits, outp);

  // 8) pos BiLSTM then pos2
  gemm_abt<<<dim3(cdiv(2848, GBN), cdiv(4096, GBM)), 256, 0, stream>>>(
      Mm, pos_Wih, pos_b, xw_all, 4096, 2848, 712);
  lstm_scan_kernel<<<2 * NWG, 512, 0, stream>>>(xw_all, pos_Whh, h0_pos, M2, 0, 4096,
                                                exbuf + 4ull * 1424,
                                                nullptr, 0, 0, nullptr);
  logits_kernel<<<4096, 256, 0, stream>>>(qac, M2, pos2_w, logits + 4096);
  softmax_4096<<<1, 256, 0, stream>>>(logits + 4096, outp + 4096);

  (void)in_sizes; (void)n_in; (void)out_size; (void)ws_size;
}